// Round 7
// baseline (8560.957 us; speedup 1.0000x reference)
//
#include <hip/hip_runtime.h>
#include <math.h>

// Problem constants
static constexpr int H  = 512;
static constexpr int B  = 32;
static constexpr int S  = 128;
static constexpr int G4 = 2048;  // 4*H
static constexpr int BH = B * H; // 16384

// ws layout (floats)
static constexpr size_t OFF_E   = 0;                        // E [t][c][b]; reused as D [b][t][c]
static constexpr size_t SZ_E    = (size_t)S * G4 * B;       // 8,388,608
static constexpr size_t OFF_EO  = OFF_E + SZ_E;             // enc_out [b][t][h]
static constexpr size_t SZ_EO   = (size_t)B * S * H;
static constexpr size_t OFF_PT  = OFF_EO + SZ_EO;           // P_t [b][h][s]
static constexpr size_t SZ_PT   = (size_t)B * H * S;
static constexpr size_t OFF_HPP = OFF_PT + SZ_PT;           // encoder h ping-pong [2][B][H]
static constexpr size_t OFF_HB  = OFF_HPP + 2 * (size_t)BH; // decoder h buf [B][H]
static constexpr size_t OFF_CB  = OFF_HB + (size_t)BH;      // c_buf [b][h]
static constexpr size_t OFF_Y   = OFF_CB + (size_t)BH;      // y [B][2048]
static constexpr size_t OFF_M1  = OFF_Y + (size_t)B * G4;   // M1 [c][2]
static constexpr size_t OFF_BE  = OFF_M1 + (size_t)G4 * 2;  // bias_e [c]
static constexpr size_t OFF_DB  = OFF_BE + G4;              // dbias [c]
static constexpr size_t OFF_END = OFF_DB + G4;              // floats end
// u32 ctrl at OFF_END: enc_htags[256*32], ytags[256*32], dhtags[32*32]
static constexpr int CTRL_U32 = (256 + 256 + 32) * 32;

__device__ __forceinline__ float sigm(float x){
  float e = __expf(-x);
  return 1.0f / (1.0f + e);
}
__device__ __forceinline__ float tanh_(float x){
  float e = __expf(2.0f * x);
  return 1.0f - 2.0f / (1.0f + e);
}

// agent-scope (coherence-point) accessors; discipline: __syncthreads (vmcnt
// drain) between data stores/loads and the tag store (validated r2-r6)
__device__ __forceinline__ float2 cload2(const float* p){
  union { unsigned long long u; float2 f; } c;
  c.u = __hip_atomic_load((const unsigned long long*)p, __ATOMIC_RELAXED,
                          __HIP_MEMORY_SCOPE_AGENT);
  return c.f;
}
__device__ __forceinline__ void cstore2(float* p, float a, float b){
  union { unsigned long long u; float2 f; } c;
  c.f = make_float2(a, b);
  __hip_atomic_store((unsigned long long*)p, c.u, __ATOMIC_RELAXED,
                     __HIP_MEMORY_SCOPE_AGENT);
}
__device__ __forceinline__ unsigned cloadu(const unsigned* p){
  return __hip_atomic_load(p, __ATOMIC_RELAXED, __HIP_MEMORY_SCOPE_AGENT);
}
__device__ __forceinline__ void cstoreu(unsigned* p, unsigned v){
  __hip_atomic_store(p, v, __ATOMIC_RELAXED, __HIP_MEMORY_SCOPE_AGENT);
}

// poll NQ tag lines (tid, tid+64, ...) until all >= target
template<int NQ>
__device__ __forceinline__ void pollN(const unsigned* base, int tid, unsigned target){
  unsigned done = 0;
  const unsigned all = (1u << NQ) - 1u;
  while (done != all){
    #pragma unroll
    for (int q = 0; q < NQ; ++q){
      if (!(done & (1u << q))){
        if (cloadu(base + (size_t)(tid + 64 * q) * 32) >= target) done |= 1u << q;
      }
    }
  }
}

// -------- prep: M1 = Wih@Wp, bias_e = Wih@bp + bih + bhh, dbias --------
__global__ __launch_bounds__(256) void prep_misc(
    const float* __restrict__ eWih, const float* __restrict__ Wp,
    const float* __restrict__ bp,  const float* __restrict__ ebih,
    const float* __restrict__ ebhh, const float* __restrict__ dbih,
    const float* __restrict__ dbhh,
    float* __restrict__ M1, float* __restrict__ bias_e, float* __restrict__ dbias)
{
  int c = blockIdx.x * 256 + threadIdx.x;   // 0..2047
  const float* wr = eWih + (size_t)c * H;
  float m0 = 0.f, m1 = 0.f, mb = 0.f;
  for (int k = 0; k < H; k += 4){
    float4 w  = *(const float4*)(wr + k);
    float4 p0 = *(const float4*)(Wp + (size_t)k * 2);
    float4 p1 = *(const float4*)(Wp + (size_t)(k + 2) * 2);
    float4 bb = *(const float4*)(bp + k);
    m0 += w.x*p0.x + w.y*p0.z + w.z*p1.x + w.w*p1.z;
    m1 += w.x*p0.y + w.y*p0.w + w.z*p1.y + w.w*p1.w;
    mb += w.x*bb.x + w.y*bb.y + w.z*bb.z + w.w*bb.w;
  }
  M1[(size_t)c*2]   = m0;
  M1[(size_t)c*2+1] = m1;
  bias_e[c] = ebih[c] + ebhh[c] + mb;
  dbias[c]  = dbih[c] + dbhh[c];
}

// -------- E fill: E[t][c][b] = M1[c]·in[b,t] + bias_e[c] --------
__global__ __launch_bounds__(256) void efill(
    const float* __restrict__ inp, const float* __restrict__ M1,
    const float* __restrict__ be, float* __restrict__ E)
{
  size_t i = (size_t)blockIdx.x * 256 + threadIdx.x;
  int b = (int)(i & 31);
  int c = (int)((i >> 5) & 2047);
  int t = (int)(i >> 16);
  float x0 = inp[((size_t)b * S + t) * 2 + 0];
  float x1 = inp[((size_t)b * S + t) * 2 + 1];
  E[i] = M1[(size_t)c*2] * x0 + M1[(size_t)c*2+1] * x1 + be[c];
}

// -------- generic fp32 GEMM: C = A(MxK) @ B(NxK)^T (+bias) --------
// LAYOUT 0: C[m*N+n]   LAYOUT 1: Pt[b][n][t] with m = b*128+t
template<int LAYOUT>
__global__ __launch_bounds__(256) void gemm_nt(
    const float* __restrict__ A, const float* __restrict__ Bm,
    const float* __restrict__ bias, float* __restrict__ C,
    int M, int N, int K)
{
  __shared__ float As[16][68];
  __shared__ float Bs[16][68];
  int tid = threadIdx.x;
  int bm = blockIdx.y * 64, bn = blockIdx.x * 64;
  int tm = (tid & 15) * 4, tn = (tid >> 4) * 4;
  float acc[4][4] = {};
  int r  = tid >> 2;
  int kq = (tid & 3) * 4;
  for (int k0 = 0; k0 < K; k0 += 16){
    float4 a = *(const float4*)(A  + (size_t)(bm + r) * K + k0 + kq);
    float4 b = *(const float4*)(Bm + (size_t)(bn + r) * K + k0 + kq);
    __syncthreads();
    As[kq+0][r] = a.x; As[kq+1][r] = a.y; As[kq+2][r] = a.z; As[kq+3][r] = a.w;
    Bs[kq+0][r] = b.x; Bs[kq+1][r] = b.y; Bs[kq+2][r] = b.z; Bs[kq+3][r] = b.w;
    __syncthreads();
    #pragma unroll
    for (int kk = 0; kk < 16; ++kk){
      float4 av = *(const float4*)(&As[kk][tm]);
      float4 bv = *(const float4*)(&Bs[kk][tn]);
      acc[0][0] += av.x*bv.x; acc[0][1] += av.x*bv.y; acc[0][2] += av.x*bv.z; acc[0][3] += av.x*bv.w;
      acc[1][0] += av.y*bv.x; acc[1][1] += av.y*bv.y; acc[1][2] += av.y*bv.z; acc[1][3] += av.y*bv.w;
      acc[2][0] += av.z*bv.x; acc[2][1] += av.z*bv.y; acc[2][2] += av.z*bv.z; acc[2][3] += av.z*bv.w;
      acc[3][0] += av.w*bv.x; acc[3][1] += av.w*bv.y; acc[3][2] += av.w*bv.z; acc[3][3] += av.w*bv.w;
    }
  }
  #pragma unroll
  for (int i = 0; i < 4; ++i){
    int m = bm + tm + i;
    #pragma unroll
    for (int j = 0; j < 4; ++j){
      int n = bn + tn + j;
      float vv = acc[i][j] + (bias ? bias[n] : 0.f);
      if (LAYOUT == 0) C[(size_t)m * N + n] = vv;
      else             C[((size_t)(m >> 7) * 512 + n) * 128 + (m & 127)] = vv;
    }
  }
}

// stage h (agent-coherent, [B][H]) into XOR-swizzled LDS
__device__ __forceinline__ void stage_h(const float* hsrc, float* hsh, int tid){
  #pragma unroll
  for (int i = tid; i < BH / 4; i += 256){
    int bb = i >> 7, k4 = i & 127;
    const float* src = hsrc + (size_t)bb * H + (k4 << 2);
    float2 lo = cload2(src), hi = cload2(src + 2);
    float4 vv; vv.x = lo.x; vv.y = lo.y; vv.z = hi.x; vv.w = hi.y;
    *(float4*)&hsh[bb * H + ((k4 ^ (bb & 7)) << 2)] = vv;
  }
}

// one-row GEMV vs swizzled LDS h-row
__device__ __forceinline__ float gemv_row(const float* __restrict__ wrow,
                                          const float* __restrict__ hb, int bx){
  float a0=0.f,a1=0.f,a2=0.f,a3=0.f;
  #pragma unroll 2
  for (int k4 = 0; k4 < 128; k4 += 4){
    float4 w0 = *(const float4*)(wrow + ((k4+0) << 2));
    float4 q0 = *(const float4*)(hb + (((k4+0) ^ bx) << 2));
    a0 = fmaf(w0.w,q0.w, fmaf(w0.z,q0.z, fmaf(w0.y,q0.y, fmaf(w0.x,q0.x, a0))));
    float4 w1 = *(const float4*)(wrow + ((k4+1) << 2));
    float4 q1 = *(const float4*)(hb + (((k4+1) ^ bx) << 2));
    a1 = fmaf(w1.w,q1.w, fmaf(w1.z,q1.z, fmaf(w1.y,q1.y, fmaf(w1.x,q1.x, a1))));
    float4 w2 = *(const float4*)(wrow + ((k4+2) << 2));
    float4 q2 = *(const float4*)(hb + (((k4+2) ^ bx) << 2));
    a2 = fmaf(w2.w,q2.w, fmaf(w2.z,q2.z, fmaf(w2.y,q2.y, fmaf(w2.x,q2.x, a2))));
    float4 w3 = *(const float4*)(wrow + ((k4+3) << 2));
    float4 q3 = *(const float4*)(hb + (((k4+3) ^ bx) << 2));
    a3 = fmaf(w3.w,q3.w, fmaf(w3.z,q3.z, fmaf(w3.y,q3.y, fmaf(w3.x,q3.x, a3))));
  }
  return (a0 + a1) + (a2 + a3);
}

// -------- persistent encoder: grid=256, 1 hop/step (r6, unchanged) --------
__global__ __launch_bounds__(256) void encoder_kernel(
    const float* __restrict__ Whh,    // enc_Whh [2048][512]
    const float* __restrict__ E,      // [t][c][b]
    float* __restrict__ h_pp,         // [2][B][H]; zeroed
    float* __restrict__ c_buf,        // [b][h]
    float* __restrict__ enc_out,      // [b][t][h]
    unsigned* __restrict__ htags)     // [256] lines
{
  __shared__ float hsh[BH];
  __shared__ float gsh[4][2][B];
  __shared__ float hloc[2][B];
  const int tid = threadIdx.x, bk = blockIdx.x;
  const int b = tid & 31, r8 = tid >> 5;
  const int gate = r8 & 3, jj = r8 >> 2;
  const int row = gate * H + bk * 2 + jj;
  const float* wrow = Whh + (size_t)row * H;
  const int bx = b & 7;
  float creg = 0.f;
  for (int t = 0; t < S; ++t){
    if (t > 0 && tid < 64) pollN<4>(htags, tid, (unsigned)t);
    __syncthreads();
    stage_h(h_pp + (size_t)((t + 1) & 1) * BH, hsh, tid);
    __syncthreads();
    float acc = gemv_row(wrow, hsh + b * H, bx);
    float ev = E[((size_t)t * G4 + row) * B + b];
    gsh[gate][jj][b] = acc + ev;
    __syncthreads();
    if (tid < 64){
      int b2 = tid & 31, j2 = tid >> 5;
      float gi = gsh[0][j2][b2], gf = gsh[1][j2][b2];
      float gg = gsh[2][j2][b2], go = gsh[3][j2][b2];
      creg = sigm(gf) * creg + sigm(gi) * tanh_(gg);
      hloc[j2][b2] = sigm(go) * tanh_(creg);
    }
    __syncthreads();
    if (tid < 32){
      float h0 = hloc[0][tid], h1 = hloc[1][tid];
      cstore2(h_pp + (size_t)(t & 1) * BH + (size_t)tid * H + bk * 2, h0, h1);
      *(float2*)(enc_out + ((size_t)tid * S + t) * H + bk * 2) = make_float2(h0, h1);
    }
    __syncthreads();   // drain publishes before tag
    if (tid == 0) cstoreu(htags + (size_t)bk * 32, (unsigned)(t + 1));
  }
  if (tid < 64){
    int b2 = tid & 31, j2 = tid >> 5;
    c_buf[(size_t)b2 * H + bk * 2 + j2] = creg;
  }
}

// -------- persistent decoder: grid=288, 2 hops/step --------
// A-blocks (0..255): y = Whh@h only (no top dependency). Owner blocks
// (256..287, one per batch): y[b] + x-term (top is OWNER-LOCAL) -> pointwise
// -> publish h; then dp/attention/argmax OFF the critical path.
// Race-freedom (single-buffer h and y): A writes y(t+1) only after
// dhtag>=t+2, which owner publishes after fully staging y(t) into LDS
// (loads drained by __syncthreads before the h-publish sync/tag). Owner
// writes h(t+1) only after ytags>=t+1, i.e. after every A-block drained its
// stage_h reads of h(t) (__syncthreads after stage precedes the y publish).
__global__ __launch_bounds__(256) void decoder_kernel(
    const float* __restrict__ Whh,    // dec_Whh [2048][512]
    const float* __restrict__ D,      // [b][t][c]
    const float* __restrict__ dbias,  // [2048]
    const float* __restrict__ W2,     // [512][512]
    const float* __restrict__ Pt,     // [b][h][s]
    const float* __restrict__ vvec,   // [512]
    const float* __restrict__ c_buf,  // [b][h]
    const float* __restrict__ enc_out,// [b][t][h]
    float* __restrict__ hbuf,         // [B][H]
    float* __restrict__ ybuf,         // [B][2048]
    unsigned* __restrict__ ytags,     // [256] lines
    unsigned* __restrict__ dhtags,    // [32] lines
    float* __restrict__ out)          // [b][t][s]
{
  __shared__ float hsh[BH];           // A: staged h. Owner: carved below.
  __shared__ float gsh[4][2][B];
  __shared__ int   topsh;
  __shared__ float wm[2]; __shared__ int wi[2]; __shared__ float wsum[2];
  const int tid = threadIdx.x, bk = blockIdx.x;
  if (bk < 256){
    // ======================= A-role =======================
    const int b = tid & 31, r8 = tid >> 5;
    const int gate = r8 & 3, jj = r8 >> 2;
    const int row = gate * H + bk * 2 + jj;
    const float* wrow = Whh + (size_t)row * H;
    const int bx = b & 7;
    for (int t = 0; t < S; ++t){
      if (tid < 32) pollN<1>(dhtags, tid, (unsigned)(t + 1));
      __syncthreads();
      stage_h(hbuf, hsh, tid);
      __syncthreads();                 // drains stage loads (h(t) fully read)
      float acc = gemv_row(wrow, hsh + b * H, bx);
      gsh[gate][jj][b] = acc;
      __syncthreads();
      if (tid < 128){
        int g2 = tid >> 5, b2 = tid & 31;
        cstore2(ybuf + (size_t)b2 * G4 + g2 * 512 + bk * 2,
                gsh[g2][0][b2], gsh[g2][1][b2]);
      }
      __syncthreads();                 // drain y stores before tag
      if (tid == 0) cstoreu(ytags + (size_t)bk * 32, (unsigned)(t + 1));
    }
  } else {
    // ======================= owner role (batch b) =======================
    const int b = bk - 256;
    float* ysh  = hsh;                 // [2048]
    float* hloc = hsh + 2048;          // [512]
    float* dpsh = hsh + 2560;          // [512]
    float* vsh  = hsh + 3072;          // [512]
    float* scsh = hsh + 3584;          // [2][128]
    vsh[tid] = vvec[tid]; vsh[tid + 256] = vvec[tid + 256];
    float c0 = c_buf[(size_t)b * H + tid];
    float c1 = c_buf[(size_t)b * H + 256 + tid];
    // initial h = enc_out[b][S-1]
    {
      float2 hi = *(const float2*)(enc_out + ((size_t)b * S + (S-1)) * H + 2 * tid);
      cstore2(hbuf + (size_t)b * H + 2 * tid, hi.x, hi.y);
    }
    __syncthreads();                   // drain before tag
    if (tid == 0) cstoreu(dhtags + (size_t)b * 32, 1u);
    for (int t = 0; t < S; ++t){
      if (tid < 64) pollN<4>(ytags, tid, (unsigned)(t + 1));
      __syncthreads();
      // stage y[b] (8KB UC)
      #pragma unroll
      for (int i = tid; i < 1024; i += 256){
        float2 q = cload2(ybuf + (size_t)b * G4 + 2 * i);
        ysh[2*i] = q.x; ysh[2*i + 1] = q.y;
      }
      __syncthreads();                 // y(t) fully read (drained)
      const float* xr = (t == 0) ? dbias
                                 : D + ((size_t)b * S + topsh) * G4;
      {
        int u = tid;
        float gi = ysh[u]        + xr[u];
        float gf = ysh[512 + u]  + xr[512 + u];
        float gg = ysh[1024 + u] + xr[1024 + u];
        float go = ysh[1536 + u] + xr[1536 + u];
        c0 = sigm(gf) * c0 + sigm(gi) * tanh_(gg);
        hloc[u] = sigm(go) * tanh_(c0);
        u = tid + 256;
        gi = ysh[u]        + xr[u];
        gf = ysh[512 + u]  + xr[512 + u];
        gg = ysh[1024 + u] + xr[1024 + u];
        go = ysh[1536 + u] + xr[1536 + u];
        c1 = sigm(gf) * c1 + sigm(gi) * tanh_(go * 0.f + gg);  // gg
        hloc[u] = sigm(go) * tanh_(c1);
      }
      __syncthreads();
      cstore2(hbuf + (size_t)b * H + 2 * tid, hloc[2*tid], hloc[2*tid + 1]);
      __syncthreads();                 // drain h publish before tag
      if (tid == 0) cstoreu(dhtags + (size_t)b * 32, (unsigned)(t + 2));
      // ---- off-critical-path: dp = h @ W2^T (2 rows/thread, cached) ----
      {
        int n = 2 * tid;
        const float* w0r = W2 + (size_t)n * H;
        const float* w1r = W2 + (size_t)(n + 1) * H;
        float d0 = 0.f, d1 = 0.f;
        #pragma unroll 2
        for (int k4 = 0; k4 < 128; ++k4){
          float4 hv = *(const float4*)&hloc[k4 << 2];
          float4 wa = *(const float4*)(w0r + (k4 << 2));
          float4 wb = *(const float4*)(w1r + (k4 << 2));
          d0 = fmaf(wa.w,hv.w, fmaf(wa.z,hv.z, fmaf(wa.y,hv.y, fmaf(wa.x,hv.x, d0))));
          d1 = fmaf(wb.w,hv.w, fmaf(wb.z,hv.z, fmaf(wb.y,hv.y, fmaf(wb.x,hv.x, d1))));
        }
        dpsh[n] = d0; dpsh[n + 1] = d1;
      }
      __syncthreads();
      // ---- attention scores ----
      {
        int s = tid & 127, half = tid >> 7;
        const float* Pp = Pt + ((size_t)b * H + half * 256) * S + s;
        const float* dq = dpsh + half * 256;
        const float* vq = vsh + half * 256;
        float cs = 0.f;
        #pragma unroll 4
        for (int hh = 0; hh < 256; ++hh){
          float x = Pp[(size_t)hh * S] + dq[hh];
          cs = fmaf(vq[hh], tanh_(x), cs);
        }
        scsh[half * S + s] = cs;
      }
      __syncthreads();
      float sc = 0.f;
      if (tid < 128){
        sc = scsh[tid] + scsh[S + tid];
        float mv = sc; int mi = tid;
        #pragma unroll
        for (int off = 32; off > 0; off >>= 1){
          float ov = __shfl_xor(mv, off, 64);
          int   oi = __shfl_xor(mi, off, 64);
          if (ov > mv || (ov == mv && oi < mi)){ mv = ov; mi = oi; }
        }
        if ((tid & 63) == 0){ wm[tid >> 6] = mv; wi[tid >> 6] = mi; }
      }
      __syncthreads();
      float m; int am;
      { float m0 = wm[0], m1 = wm[1];
        if (m1 > m0 || (m1 == m0 && wi[1] < wi[0])){ m = m1; am = wi[1]; }
        else { m = m0; am = wi[0]; } }
      if (tid < 128){
        float se = __expf(sc - m);
        float ss = se;
        #pragma unroll
        for (int off = 32; off > 0; off >>= 1) ss += __shfl_xor(ss, off, 64);
        if ((tid & 63) == 0) wsum[tid >> 6] = ss;
      }
      __syncthreads();
      float lse = __logf(wsum[0] + wsum[1]);
      if (tid < 128) out[((size_t)b * S + t) * S + tid] = sc - m - lse;
      if (tid == 0) topsh = am;
      __syncthreads();
    }
  }
}

extern "C" void kernel_launch(void* const* d_in, const int* in_sizes, int n_in,
                              void* d_out, int out_size, void* d_ws, size_t ws_size,
                              hipStream_t stream) {
  const float* inputs  = (const float*)d_in[0];
  const float* Wp      = (const float*)d_in[1];
  const float* bp      = (const float*)d_in[2];
  const float* eWih    = (const float*)d_in[3];
  const float* eWhh    = (const float*)d_in[4];
  const float* ebih    = (const float*)d_in[5];
  const float* ebhh    = (const float*)d_in[6];
  const float* dWih    = (const float*)d_in[7];
  const float* dWhh    = (const float*)d_in[8];
  const float* dbih    = (const float*)d_in[9];
  const float* dbhh    = (const float*)d_in[10];
  const float* W1      = (const float*)d_in[11];
  const float* W2      = (const float*)d_in[12];
  const float* v       = (const float*)d_in[13];
  float* out = (float*)d_out;

  float* ws = (float*)d_ws;
  float* E       = ws + OFF_E;    // reused as D after encoder
  float* enc_out = ws + OFF_EO;
  float* Pt      = ws + OFF_PT;
  float* h_pp    = ws + OFF_HPP;
  float* hbuf    = ws + OFF_HB;
  float* c_buf   = ws + OFF_CB;
  float* ybuf    = ws + OFF_Y;
  float* M1      = ws + OFF_M1;
  float* bias_e  = ws + OFF_BE;
  float* dbias   = ws + OFF_DB;
  unsigned* enc_htags = (unsigned*)(ws + OFF_END);
  unsigned* ytags     = enc_htags + 256 * 32;
  unsigned* dhtags    = ytags + 256 * 32;

  // deterministic per launch: zero encoder h ping-pong + all tag lines
  hipMemsetAsync(h_pp, 0, 2 * (size_t)BH * sizeof(float), stream);
  hipMemsetAsync(enc_htags, 0, CTRL_U32 * sizeof(unsigned), stream);

  prep_misc<<<G4 / 256, 256, 0, stream>>>(eWih, Wp, bp, ebih, ebhh, dbih, dbhh,
                                          M1, bias_e, dbias);
  efill<<<(int)(SZ_E / 256), 256, 0, stream>>>(inputs, M1, bias_e, E);

  encoder_kernel<<<256, 256, 0, stream>>>(eWhh, E, h_pp, c_buf, enc_out, enc_htags);

  // D = enc_out @ dWih^T + dbias (into E's buffer; encoder is done with E)
  float* D = E;
  { dim3 grid(G4 / 64, (B * S) / 64);
    gemm_nt<0><<<grid, 256, 0, stream>>>(enc_out, dWih, dbias, D, B * S, G4, H); }
  { dim3 grid(H / 64, (B * S) / 64);
    gemm_nt<1><<<grid, 256, 0, stream>>>(enc_out, W1, nullptr, Pt, B * S, H, H); }

  decoder_kernel<<<288, 256, 0, stream>>>(dWhh, D, dbias, W2, Pt, v, c_buf,
                                          enc_out, hbuf, ybuf, ytags, dhtags, out);
  (void)in_sizes; (void)n_in; (void)out_size; (void)ws_size;
}

// Round 8
// 4224.630 us; speedup vs baseline: 2.0264x; 2.0264x over previous
//
#include <hip/hip_runtime.h>
#include <math.h>

// Problem constants
static constexpr int H   = 512;
static constexpr int B   = 32;
static constexpr int S   = 128;
static constexpr int G4  = 2048;  // 4*H
static constexpr int UPS = 64;    // units per slice
static constexpr int RPS = 256;   // rows per slice (4 gates * UPS)
static constexpr int NSL = 8;     // slices per batch

// ws layout (floats)
static constexpr size_t OFF_E   = 0;                          // E [b][t][c]; reused as D
static constexpr size_t SZ_E    = (size_t)B * S * G4;         // 8,388,608
static constexpr size_t OFF_EO  = OFF_E + SZ_E;               // enc_out [b][t][h]
static constexpr size_t SZ_EO   = (size_t)B * S * H;
static constexpr size_t OFF_PT  = OFF_EO + SZ_EO;             // P_t [b][h][s]
static constexpr size_t SZ_PT   = (size_t)B * H * S;
static constexpr size_t OFF_WPE = OFF_PT + SZ_PT;             // packed enc Whh [8][512][256]
static constexpr size_t SZ_WP   = (size_t)NSL * H * RPS;      // 1,048,576
static constexpr size_t OFF_WPD = OFF_WPE + SZ_WP;            // packed dec Whh
static constexpr size_t OFF_W2T = OFF_WPD + SZ_WP;            // W2T [512][512]
static constexpr size_t OFF_HB  = OFF_W2T + (size_t)H * H;    // hb [B][2][H]
static constexpr size_t OFF_CB  = OFF_HB + (size_t)B * 2 * H; // c_buf [B][H]
static constexpr size_t OFF_DPB = OFF_CB + (size_t)B * H;     // dpb [B][2][H]
static constexpr size_t OFF_M1  = OFF_DPB + (size_t)B * 2 * H;
static constexpr size_t OFF_BE  = OFF_M1 + (size_t)G4 * 2;
static constexpr size_t OFF_DB  = OFF_BE + G4;
static constexpr size_t OFF_END = OFF_DB + G4;
// u32 ctrl at OFF_END: htags_e[256*32], htags_d[256*32], dptags[256*32], tops[32*32]
static constexpr int CTRL_U32 = (256 + 256 + 256 + 32) * 32;

__device__ __forceinline__ float sigm(float x){
  float e = __expf(-x);
  return 1.0f / (1.0f + e);
}
__device__ __forceinline__ float tanh_(float x){
  float e = __expf(2.0f * x);
  return 1.0f - 2.0f / (1.0f + e);
}

// agent-scope (coherence-point) accessors; discipline: __syncthreads (vmcnt
// drain) between data stores/loads and the tag store (validated r2-r7)
__device__ __forceinline__ float2 cload2(const float* p){
  union { unsigned long long u; float2 f; } c;
  c.u = __hip_atomic_load((const unsigned long long*)p, __ATOMIC_RELAXED,
                          __HIP_MEMORY_SCOPE_AGENT);
  return c.f;
}
__device__ __forceinline__ void cstore2(float* p, float a, float b){
  union { unsigned long long u; float2 f; } c;
  c.f = make_float2(a, b);
  __hip_atomic_store((unsigned long long*)p, c.u, __ATOMIC_RELAXED,
                     __HIP_MEMORY_SCOPE_AGENT);
}
__device__ __forceinline__ unsigned cloadu(const unsigned* p){
  return __hip_atomic_load(p, __ATOMIC_RELAXED, __HIP_MEMORY_SCOPE_AGENT);
}
__device__ __forceinline__ void cstoreu(unsigned* p, unsigned v){
  __hip_atomic_store(p, v, __ATOMIC_RELAXED, __HIP_MEMORY_SCOPE_AGENT);
}

// -------- prep: M1 = Wih@Wp, bias_e = Wih@bp + bih + bhh, dbias --------
__global__ __launch_bounds__(256) void prep_misc(
    const float* __restrict__ eWih, const float* __restrict__ Wp,
    const float* __restrict__ bp,  const float* __restrict__ ebih,
    const float* __restrict__ ebhh, const float* __restrict__ dbih,
    const float* __restrict__ dbhh,
    float* __restrict__ M1, float* __restrict__ bias_e, float* __restrict__ dbias)
{
  int c = blockIdx.x * 256 + threadIdx.x;   // 0..2047
  const float* wr = eWih + (size_t)c * H;
  float m0 = 0.f, m1 = 0.f, mb = 0.f;
  for (int k = 0; k < H; k += 4){
    float4 w  = *(const float4*)(wr + k);
    float4 p0 = *(const float4*)(Wp + (size_t)k * 2);
    float4 p1 = *(const float4*)(Wp + (size_t)(k + 2) * 2);
    float4 bb = *(const float4*)(bp + k);
    m0 += w.x*p0.x + w.y*p0.z + w.z*p1.x + w.w*p1.z;
    m1 += w.x*p0.y + w.y*p0.w + w.z*p1.y + w.w*p1.w;
    mb += w.x*bb.x + w.y*bb.y + w.z*bb.z + w.w*bb.w;
  }
  M1[(size_t)c*2]   = m0;
  M1[(size_t)c*2+1] = m1;
  bias_e[c] = ebih[c] + ebhh[c] + mb;
  dbias[c]  = dbih[c] + dbhh[c];
}

// -------- E fill: E[b][t][c] = M1[c]·in[b,t] + bias_e[c] --------
__global__ __launch_bounds__(256) void efill(
    const float* __restrict__ inp, const float* __restrict__ M1,
    const float* __restrict__ be, float* __restrict__ E)
{
  size_t i = (size_t)blockIdx.x * 256 + threadIdx.x;
  int c = (int)(i & 2047);
  int t = (int)((i >> 11) & 127);
  int b = (int)(i >> 18);
  float x0 = inp[((size_t)b * S + t) * 2 + 0];
  float x1 = inp[((size_t)b * S + t) * 2 + 1];
  E[i] = M1[(size_t)c*2] * x0 + M1[(size_t)c*2+1] * x1 + be[c];
}

// -------- pack Whh into per-slice contiguous form WP[j][k][g*64+u] --------
__global__ __launch_bounds__(256) void pack_whh(
    const float* __restrict__ Whh, float* __restrict__ WP)
{
  size_t i = (size_t)blockIdx.x * 256 + threadIdx.x;  // 1,048,576
  int p = (int)(i & 255);          // g*64+u
  int k = (int)((i >> 8) & 511);
  int j = (int)(i >> 17);
  int g = p >> 6, u = p & 63;
  int r = g * 512 + j * UPS + u;
  WP[i] = Whh[(size_t)r * H + k];
}

// -------- transpose: out[K][R] = in[R][K] --------
__global__ __launch_bounds__(256) void transpose_k(
    const float* __restrict__ in, float* __restrict__ out, int R, int K)
{
  __shared__ float tile[32][33];
  int r0 = blockIdx.y * 32, k0 = blockIdx.x * 32;
  int tx = threadIdx.x & 31, ty = threadIdx.x >> 5;
  #pragma unroll
  for (int j = 0; j < 4; ++j)
    tile[ty + 8*j][tx] = in[(size_t)(r0 + ty + 8*j) * K + k0 + tx];
  __syncthreads();
  #pragma unroll
  for (int j = 0; j < 4; ++j)
    out[(size_t)(k0 + ty + 8*j) * R + r0 + tx] = tile[tx][ty + 8*j];
}

// -------- generic fp32 GEMM: C = A(MxK) @ B(NxK)^T (+bias) --------
template<int LAYOUT>
__global__ __launch_bounds__(256) void gemm_nt(
    const float* __restrict__ A, const float* __restrict__ Bm,
    const float* __restrict__ bias, float* __restrict__ C,
    int M, int N, int K)
{
  __shared__ float As[16][68];
  __shared__ float Bs[16][68];
  int tid = threadIdx.x;
  int bm = blockIdx.y * 64, bn = blockIdx.x * 64;
  int tm = (tid & 15) * 4, tn = (tid >> 4) * 4;
  float acc[4][4] = {};
  int r  = tid >> 2;
  int kq = (tid & 3) * 4;
  for (int k0 = 0; k0 < K; k0 += 16){
    float4 a = *(const float4*)(A  + (size_t)(bm + r) * K + k0 + kq);
    float4 b = *(const float4*)(Bm + (size_t)(bn + r) * K + k0 + kq);
    __syncthreads();
    As[kq+0][r] = a.x; As[kq+1][r] = a.y; As[kq+2][r] = a.z; As[kq+3][r] = a.w;
    Bs[kq+0][r] = b.x; Bs[kq+1][r] = b.y; Bs[kq+2][r] = b.z; Bs[kq+3][r] = b.w;
    __syncthreads();
    #pragma unroll
    for (int kk = 0; kk < 16; ++kk){
      float4 av = *(const float4*)(&As[kk][tm]);
      float4 bv = *(const float4*)(&Bs[kk][tn]);
      acc[0][0] += av.x*bv.x; acc[0][1] += av.x*bv.y; acc[0][2] += av.x*bv.z; acc[0][3] += av.x*bv.w;
      acc[1][0] += av.y*bv.x; acc[1][1] += av.y*bv.y; acc[1][2] += av.y*bv.z; acc[1][3] += av.y*bv.w;
      acc[2][0] += av.z*bv.x; acc[2][1] += av.z*bv.y; acc[2][2] += av.z*bv.z; acc[2][3] += av.z*bv.w;
      acc[3][0] += av.w*bv.x; acc[3][1] += av.w*bv.y; acc[3][2] += av.w*bv.z; acc[3][3] += av.w*bv.w;
    }
  }
  #pragma unroll
  for (int i = 0; i < 4; ++i){
    int m = bm + tm + i;
    #pragma unroll
    for (int j = 0; j < 4; ++j){
      int n = bn + tn + j;
      float vv = acc[i][j] + (bias ? bias[n] : 0.f);
      if (LAYOUT == 0) C[(size_t)m * N + n] = vv;
      else             C[((size_t)(m >> 7) * 512 + n) * 128 + (m & 127)] = vv;
    }
  }
}

// -------- per-batch-group encoder: 8 blocks/batch, grid=256 --------
// Block bk: b = bk>>3, j = bk&7 owns units [j*64, j*64+64).
// htag value = t+1 once h(t) slice published. Step t stages h(t-1) from
// hb[b][(t-1)&1]; safe 2-deep ping-pong: writing h(t+2) over h(t) requires
// htags>=t+2, which implies every block staged h(t) (stage precedes publish
// in program order, drained by __syncthreads).
__global__ __launch_bounds__(256) void encoder_kernel(
    const float* __restrict__ WP,     // [8][512][256]
    const float* __restrict__ E,      // [b][t][2048]
    float* __restrict__ hb,           // [B][2][H] (zeroed)
    float* __restrict__ c_buf,        // [B][H]
    float* __restrict__ enc_out,      // [b][t][h]
    unsigned* __restrict__ htags)     // 256 lines, (b*8+j)*32
{
  __shared__ float hsh[H];
  __shared__ float gpart[4][RPS];
  __shared__ float gfin[4][UPS];
  __shared__ float hloc[UPS];
  const int tid = threadIdx.x, bk = blockIdx.x;
  const int b = bk >> 3, j = bk & 7;
  const int u0 = j * UPS;
  const float* wp = WP + (size_t)j * H * RPS;
  unsigned* myhtags = htags + (size_t)b * 8 * 32;
  const int ph = tid >> 6, c4 = tid & 63;
  float creg = 0.f;
  for (int t = 0; t < S; ++t){
    if (t > 0 && tid < 8){
      while (cloadu(myhtags + tid * 32) < (unsigned)t){}
    }
    __syncthreads();
    { float2 q = cload2(hb + ((size_t)b * 2 + ((t + 1) & 1)) * H + 2 * tid);
      hsh[2*tid] = q.x; hsh[2*tid + 1] = q.y; }
    __syncthreads();
    // gates gemv: phase ph covers k = 4kk+ph; cols 4c4..4c4+3
    float4 acc = {0.f, 0.f, 0.f, 0.f};
    const float* wq = wp + ph * RPS + c4 * 4;
    #pragma unroll 4
    for (int kk = 0; kk < 128; ++kk){
      float hv = hsh[4*kk + ph];
      float4 w = *(const float4*)(wq + (size_t)kk * 4 * RPS);
      acc.x = fmaf(w.x, hv, acc.x); acc.y = fmaf(w.y, hv, acc.y);
      acc.z = fmaf(w.z, hv, acc.z); acc.w = fmaf(w.w, hv, acc.w);
    }
    *(float4*)&gpart[ph][c4 * 4] = acc;
    __syncthreads();
    if (tid < 64){
      float4 s0 = *(const float4*)&gpart[0][tid*4];
      float4 s1 = *(const float4*)&gpart[1][tid*4];
      float4 s2 = *(const float4*)&gpart[2][tid*4];
      float4 s3 = *(const float4*)&gpart[3][tid*4];
      int g = tid >> 4, uu = (tid & 15) * 4;
      float4 e = *(const float4*)(E + ((size_t)b * S + t) * G4 + g * 512 + u0 + uu);
      float4 s; s.x = s0.x+s1.x+s2.x+s3.x + e.x; s.y = s0.y+s1.y+s2.y+s3.y + e.y;
      s.z = s0.z+s1.z+s2.z+s3.z + e.z; s.w = s0.w+s1.w+s2.w+s3.w + e.w;
      *(float4*)&gfin[g][uu] = s;
    }
    __syncthreads();
    if (tid < UPS){
      float gi = gfin[0][tid], gf = gfin[1][tid], gg = gfin[2][tid], go = gfin[3][tid];
      creg = sigm(gf) * creg + sigm(gi) * tanh_(gg);
      hloc[tid] = sigm(go) * tanh_(creg);
    }
    __syncthreads();
    if (tid < 32){
      float h0 = hloc[2*tid], h1 = hloc[2*tid + 1];
      cstore2(hb + ((size_t)b * 2 + (t & 1)) * H + u0 + 2*tid, h0, h1);
      *(float2*)(enc_out + ((size_t)b * S + t) * H + u0 + 2*tid) = make_float2(h0, h1);
    }
    __syncthreads();   // drain publishes before tag
    if (tid == 0) cstoreu(myhtags + j * 32, (unsigned)(t + 1));
  }
  if (tid < UPS) c_buf[(size_t)b * H + u0 + tid] = creg;
}

// -------- per-batch-group decoder: 8 gemv + 1 attn per batch, grid=288 --------
// gemv (bk<256, b=bk>>3, j=bk&7): step t: stage h(t-1); publish dp(t-1) slice
// (dptag=t); gates gemv; poll toptag==t; pointwise; publish h(t) (htag=t+1).
// Epilogue publishes dp(127) (dptag=128). Initial h(-1)=enc h(127) at hb[b][1]
// (kernel boundary visibility). attn (bk>=256, b=bk-256): iter τ: poll dptags
// >=τ+1; stage dp(τ); scores+argmax; publish toptag=((τ+1)<<8)|idx; softmax;
// out row τ. dp ping-pong safety: overwrite of dp(τ) parity at step τ+3 is
// gated by toptag>=τ+2, published after attn staged dp(τ+1) ⊇ finished dp(τ).
__global__ __launch_bounds__(256) void decoder_kernel(
    const float* __restrict__ WP,     // [8][512][256]
    const float* __restrict__ D,      // [b][t][2048]
    const float* __restrict__ dbias,  // [2048]
    const float* __restrict__ W2T,    // [512][512]
    const float* __restrict__ Pt,     // [b][h][s]
    const float* __restrict__ vvec,   // [512]
    const float* __restrict__ c_buf,  // [B][H]
    float* __restrict__ hb,           // [B][2][H]
    float* __restrict__ dpb,          // [B][2][H]
    unsigned* __restrict__ htags,     // 256 lines
    unsigned* __restrict__ dptags,    // 256 lines
    unsigned* __restrict__ tops,      // 32 lines
    float* __restrict__ out)          // [b][t][s]
{
  __shared__ float hsh[H];
  __shared__ float gpart[4][RPS];
  __shared__ float gfin[4][UPS];
  __shared__ float hloc[UPS];
  __shared__ float gdp[4][UPS];
  __shared__ float dloc[UPS];
  __shared__ int   topsh;
  __shared__ float dpsh[H];
  __shared__ float vsh[H];
  __shared__ float scsh[2][S];
  __shared__ float wm[2]; __shared__ int wi[2]; __shared__ float wsum[2];
  const int tid = threadIdx.x, bk = blockIdx.x;
  if (bk < 256){
    // =================== gemv role ===================
    const int b = bk >> 3, j = bk & 7;
    const int u0 = j * UPS;
    const float* wp = WP + (size_t)j * H * RPS;
    unsigned* myhtags = htags + (size_t)b * 8 * 32;
    const int ph = tid >> 6, c4 = tid & 63;
    float creg = (tid < UPS) ? c_buf[(size_t)b * H + u0 + tid] : 0.f;
    for (int t = 0; t < S; ++t){
      if (t > 0 && tid < 8){
        while (cloadu(myhtags + tid * 32) < (unsigned)t){}
      }
      __syncthreads();
      { float2 q = cload2(hb + ((size_t)b * 2 + ((t + 1) & 1)) * H + 2 * tid);
        hsh[2*tid] = q.x; hsh[2*tid + 1] = q.y; }
      __syncthreads();
      // dp(t-1) slice: 64 cols of W2T, partial over k-quarter
      if (t >= 1){
        int nl = tid & 63, kq = tid >> 6;
        const float* w = W2T + (size_t)(kq * 128) * H + u0 + nl;
        float a = 0.f;
        #pragma unroll 8
        for (int k2 = 0; k2 < 128; ++k2)
          a = fmaf(w[(size_t)k2 * H], hsh[kq * 128 + k2], a);
        gdp[kq][nl] = a;
        __syncthreads();
        if (tid < UPS) dloc[tid] = gdp[0][tid] + gdp[1][tid] + gdp[2][tid] + gdp[3][tid];
        __syncthreads();
        if (tid < 32)
          cstore2(dpb + ((size_t)b * 2 + ((t - 1) & 1)) * H + u0 + 2*tid,
                  dloc[2*tid], dloc[2*tid + 1]);
        __syncthreads();   // drain dp publish before tag
        if (tid == 0) cstoreu(dptags + (size_t)(b * 8 + j) * 32, (unsigned)t);
      }
      // gates gemv
      float4 acc = {0.f, 0.f, 0.f, 0.f};
      const float* wq = wp + ph * RPS + c4 * 4;
      #pragma unroll 4
      for (int kk = 0; kk < 128; ++kk){
        float hv = hsh[4*kk + ph];
        float4 w = *(const float4*)(wq + (size_t)kk * 4 * RPS);
        acc.x = fmaf(w.x, hv, acc.x); acc.y = fmaf(w.y, hv, acc.y);
        acc.z = fmaf(w.z, hv, acc.z); acc.w = fmaf(w.w, hv, acc.w);
      }
      *(float4*)&gpart[ph][c4 * 4] = acc;
      // toptag poll (top(t-1)) — hidden behind the gemv stream
      if (t > 0 && tid == 0){
        unsigned vt;
        do { vt = cloadu(tops + (size_t)b * 32); } while ((vt >> 8) != (unsigned)t);
        topsh = (int)(vt & 255u);
      }
      __syncthreads();
      if (tid < 64){
        float4 s0 = *(const float4*)&gpart[0][tid*4];
        float4 s1 = *(const float4*)&gpart[1][tid*4];
        float4 s2 = *(const float4*)&gpart[2][tid*4];
        float4 s3 = *(const float4*)&gpart[3][tid*4];
        int g = tid >> 4, uu = (tid & 15) * 4;
        const float* xr = (t == 0) ? dbias : D + ((size_t)b * S + topsh) * G4;
        float4 e = *(const float4*)(xr + g * 512 + u0 + uu);
        float4 s; s.x = s0.x+s1.x+s2.x+s3.x + e.x; s.y = s0.y+s1.y+s2.y+s3.y + e.y;
        s.z = s0.z+s1.z+s2.z+s3.z + e.z; s.w = s0.w+s1.w+s2.w+s3.w + e.w;
        *(float4*)&gfin[g][uu] = s;
      }
      __syncthreads();
      if (tid < UPS){
        float gi = gfin[0][tid], gf = gfin[1][tid], gg = gfin[2][tid], go = gfin[3][tid];
        creg = sigm(gf) * creg + sigm(gi) * tanh_(gg);
        hloc[tid] = sigm(go) * tanh_(creg);
      }
      __syncthreads();
      if (tid < 32)
        cstore2(hb + ((size_t)b * 2 + (t & 1)) * H + u0 + 2*tid,
                hloc[2*tid], hloc[2*tid + 1]);
      __syncthreads();   // drain h publish before tag
      if (tid == 0) cstoreu(myhtags + j * 32, (unsigned)(t + 1));
    }
    // epilogue: dp(127)
    if (tid < 8){
      while (cloadu(myhtags + tid * 32) < (unsigned)S){}
    }
    __syncthreads();
    { float2 q = cload2(hb + ((size_t)b * 2 + ((S - 1) & 1)) * H + 2 * tid);
      hsh[2*tid] = q.x; hsh[2*tid + 1] = q.y; }
    __syncthreads();
    {
      int nl = tid & 63, kq = tid >> 6;
      const float* w = W2T + (size_t)(kq * 128) * H + u0 + nl;
      float a = 0.f;
      #pragma unroll 8
      for (int k2 = 0; k2 < 128; ++k2)
        a = fmaf(w[(size_t)k2 * H], hsh[kq * 128 + k2], a);
      gdp[kq][nl] = a;
    }
    __syncthreads();
    if (tid < UPS) dloc[tid] = gdp[0][tid] + gdp[1][tid] + gdp[2][tid] + gdp[3][tid];
    __syncthreads();
    if (tid < 32)
      cstore2(dpb + ((size_t)b * 2 + ((S - 1) & 1)) * H + u0 + 2*tid,
              dloc[2*tid], dloc[2*tid + 1]);
    __syncthreads();
    if (tid == 0) cstoreu(dptags + (size_t)(b * 8 + j) * 32, (unsigned)S);
  } else {
    // =================== attention role ===================
    const int b = bk - 256;
    vsh[tid] = vvec[tid]; vsh[tid + 256] = vvec[tid + 256];
    for (int t = 0; t < S; ++t){
      if (tid < 8){
        while (cloadu(dptags + (size_t)(b * 8 + tid) * 32) < (unsigned)(t + 1)){}
      }
      __syncthreads();
      { float2 q = cload2(dpb + ((size_t)b * 2 + (t & 1)) * H + 2 * tid);
        dpsh[2*tid] = q.x; dpsh[2*tid + 1] = q.y; }
      __syncthreads();
      int s = tid & 127, half = tid >> 7;
      const float* Pp = Pt + ((size_t)b * H + half * 256) * S + s;
      const float* dq = dpsh + half * 256;
      const float* vq = vsh + half * 256;
      float cs = 0.f;
      #pragma unroll 4
      for (int hh = 0; hh < 256; ++hh){
        float x = Pp[(size_t)hh * S] + dq[hh];
        cs = fmaf(vq[hh], tanh_(x), cs);
      }
      scsh[half][s] = cs;
      __syncthreads();
      float sc = 0.f;
      if (tid < 128){
        sc = scsh[0][tid] + scsh[1][tid];
        float mv = sc; int mi = tid;
        #pragma unroll
        for (int off = 32; off > 0; off >>= 1){
          float ov = __shfl_xor(mv, off, 64);
          int   oi = __shfl_xor(mi, off, 64);
          if (ov > mv || (ov == mv && oi < mi)){ mv = ov; mi = oi; }
        }
        if ((tid & 63) == 0){ wm[tid >> 6] = mv; wi[tid >> 6] = mi; }
      }
      __syncthreads();
      float m; int am;
      { float m0 = wm[0], m1 = wm[1];
        if (m1 > m0 || (m1 == m0 && wi[1] < wi[0])){ m = m1; am = wi[1]; }
        else { m = m0; am = wi[0]; } }
      // publish top early (dpsh fully staged at the stage-sync above)
      if (tid == 0) cstoreu(tops + (size_t)b * 32, ((unsigned)(t + 1) << 8) | (unsigned)am);
      if (tid < 128){
        float se = __expf(sc - m);
        float ss = se;
        #pragma unroll
        for (int off = 32; off > 0; off >>= 1) ss += __shfl_xor(ss, off, 64);
        if ((tid & 63) == 0) wsum[tid >> 6] = ss;
      }
      __syncthreads();
      float lse = __logf(wsum[0] + wsum[1]);
      if (tid < 128) out[((size_t)b * S + t) * S + tid] = sc - m - lse;
      __syncthreads();
    }
  }
}

extern "C" void kernel_launch(void* const* d_in, const int* in_sizes, int n_in,
                              void* d_out, int out_size, void* d_ws, size_t ws_size,
                              hipStream_t stream) {
  const float* inputs  = (const float*)d_in[0];
  const float* Wp      = (const float*)d_in[1];
  const float* bp      = (const float*)d_in[2];
  const float* eWih    = (const float*)d_in[3];
  const float* eWhh    = (const float*)d_in[4];
  const float* ebih    = (const float*)d_in[5];
  const float* ebhh    = (const float*)d_in[6];
  const float* dWih    = (const float*)d_in[7];
  const float* dWhh    = (const float*)d_in[8];
  const float* dbih    = (const float*)d_in[9];
  const float* dbhh    = (const float*)d_in[10];
  const float* W1      = (const float*)d_in[11];
  const float* W2      = (const float*)d_in[12];
  const float* v       = (const float*)d_in[13];
  float* out = (float*)d_out;

  float* ws = (float*)d_ws;
  float* E       = ws + OFF_E;    // reused as D after encoder
  float* enc_out = ws + OFF_EO;
  float* Pt      = ws + OFF_PT;
  float* WPe     = ws + OFF_WPE;
  float* WPd     = ws + OFF_WPD;
  float* W2T     = ws + OFF_W2T;
  float* hb      = ws + OFF_HB;
  float* c_buf   = ws + OFF_CB;
  float* dpb     = ws + OFF_DPB;
  float* M1      = ws + OFF_M1;
  float* bias_e  = ws + OFF_BE;
  float* dbias   = ws + OFF_DB;
  unsigned* htags_e = (unsigned*)(ws + OFF_END);
  unsigned* htags_d = htags_e + 256 * 32;
  unsigned* dptags  = htags_d + 256 * 32;
  unsigned* tops    = dptags + 256 * 32;

  // deterministic per launch: zero h buffers + all tag lines
  hipMemsetAsync(hb, 0, (size_t)B * 2 * H * sizeof(float), stream);
  hipMemsetAsync(htags_e, 0, CTRL_U32 * sizeof(unsigned), stream);

  prep_misc<<<G4 / 256, 256, 0, stream>>>(eWih, Wp, bp, ebih, ebhh, dbih, dbhh,
                                          M1, bias_e, dbias);
  efill<<<(int)(SZ_E / 256), 256, 0, stream>>>(inputs, M1, bias_e, E);
  pack_whh<<<(int)(SZ_WP / 256), 256, 0, stream>>>(eWhh, WPe);
  pack_whh<<<(int)(SZ_WP / 256), 256, 0, stream>>>(dWhh, WPd);
  { dim3 g(H / 32, H / 32); transpose_k<<<g, 256, 0, stream>>>(W2, W2T, H, H); }

  encoder_kernel<<<256, 256, 0, stream>>>(WPe, E, hb, c_buf, enc_out, htags_e);

  // D = enc_out @ dWih^T + dbias (into E's buffer; encoder is done with E)
  float* D = E;
  { dim3 grid(G4 / 64, (B * S) / 64);
    gemm_nt<0><<<grid, 256, 0, stream>>>(enc_out, dWih, dbias, D, B * S, G4, H); }
  { dim3 grid(H / 64, (B * S) / 64);
    gemm_nt<1><<<grid, 256, 0, stream>>>(enc_out, W1, nullptr, Pt, B * S, H, H); }

  decoder_kernel<<<288, 256, 0, stream>>>(WPd, D, dbias, W2T, Pt, v, c_buf,
                                          hb, dpb, htags_d, dptags, tops, out);
  (void)in_sizes; (void)n_in; (void)out_size; (void)ws_size;
}

// Round 9
// 3170.273 us; speedup vs baseline: 2.7004x; 1.3326x over previous
//
#include <hip/hip_runtime.h>
#include <math.h>

// Problem constants
static constexpr int H   = 512;
static constexpr int B   = 32;
static constexpr int S   = 128;
static constexpr int G4  = 2048;  // 4*H
static constexpr int UPS = 64;    // units per y-slice
static constexpr int RPS = 256;   // rows per y-slice (4 gates * UPS)
static constexpr int NSL = 8;     // y-slices per batch

// ws layout (floats)
static constexpr size_t OFF_E   = 0;                          // E [b][t][c]; reused as D
static constexpr size_t SZ_E    = (size_t)B * S * G4;         // 8,388,608
static constexpr size_t OFF_EO  = OFF_E + SZ_E;               // enc_out [b][t][h]
static constexpr size_t SZ_EO   = (size_t)B * S * H;
static constexpr size_t OFF_PT  = OFF_EO + SZ_EO;             // P_t [b][h][s]
static constexpr size_t SZ_PT   = (size_t)B * H * S;
static constexpr size_t OFF_WPE = OFF_PT + SZ_PT;             // packed enc Whh [8][512][256]
static constexpr size_t SZ_WP   = (size_t)NSL * H * RPS;      // 1,048,576
static constexpr size_t OFF_WPD = OFF_WPE + SZ_WP;            // packed dec Whh
static constexpr size_t OFF_W2T = OFF_WPD + SZ_WP;            // W2T [512][512]
static constexpr size_t OFF_HB  = OFF_W2T + (size_t)H * H;    // hb [B][2][H]
static constexpr size_t OFF_CB  = OFF_HB + (size_t)B * 2 * H; // c_buf [B][H]
static constexpr size_t OFF_YB  = OFF_CB + (size_t)B * H;     // ybuf [B][2048]
static constexpr size_t OFF_PS  = OFF_YB + (size_t)B * G4;    // psbuf [B][4][128]
static constexpr size_t OFF_M1  = OFF_PS + (size_t)B * 512;
static constexpr size_t OFF_BE  = OFF_M1 + (size_t)G4 * 2;
static constexpr size_t OFF_DB  = OFF_BE + G4;
static constexpr size_t OFF_END = OFF_DB + G4;
// u32 ctrl at OFF_END: enc_htags[256*32], dec_htag[32*32], wtags[384*32]
static constexpr int CTRL_U32 = (256 + 32 + 384) * 32;

__device__ __forceinline__ float sigm(float x){
  float e = __expf(-x);
  return 1.0f / (1.0f + e);
}
__device__ __forceinline__ float tanh_(float x){
  float e = __expf(2.0f * x);
  return 1.0f - 2.0f / (1.0f + e);
}

// agent-scope (coherence-point) accessors; discipline: __syncthreads (vmcnt
// drain) between data stores/loads and the tag store (validated r2-r8)
__device__ __forceinline__ float cloadf(const float* p){
  union { unsigned u; float f; } c;
  c.u = __hip_atomic_load((const unsigned*)p, __ATOMIC_RELAXED,
                          __HIP_MEMORY_SCOPE_AGENT);
  return c.f;
}
__device__ __forceinline__ float2 cload2(const float* p){
  union { unsigned long long u; float2 f; } c;
  c.u = __hip_atomic_load((const unsigned long long*)p, __ATOMIC_RELAXED,
                          __HIP_MEMORY_SCOPE_AGENT);
  return c.f;
}
__device__ __forceinline__ void cstore2(float* p, float a, float b){
  union { unsigned long long u; float2 f; } c;
  c.f = make_float2(a, b);
  __hip_atomic_store((unsigned long long*)p, c.u, __ATOMIC_RELAXED,
                     __HIP_MEMORY_SCOPE_AGENT);
}
__device__ __forceinline__ unsigned cloadu(const unsigned* p){
  return __hip_atomic_load(p, __ATOMIC_RELAXED, __HIP_MEMORY_SCOPE_AGENT);
}
__device__ __forceinline__ void cstoreu(unsigned* p, unsigned v){
  __hip_atomic_store(p, v, __ATOMIC_RELAXED, __HIP_MEMORY_SCOPE_AGENT);
}

// -------- prep: M1 = Wih@Wp, bias_e = Wih@bp + bih + bhh, dbias --------
__global__ __launch_bounds__(256) void prep_misc(
    const float* __restrict__ eWih, const float* __restrict__ Wp,
    const float* __restrict__ bp,  const float* __restrict__ ebih,
    const float* __restrict__ ebhh, const float* __restrict__ dbih,
    const float* __restrict__ dbhh,
    float* __restrict__ M1, float* __restrict__ bias_e, float* __restrict__ dbias)
{
  int c = blockIdx.x * 256 + threadIdx.x;   // 0..2047
  const float* wr = eWih + (size_t)c * H;
  float m0 = 0.f, m1 = 0.f, mb = 0.f;
  for (int k = 0; k < H; k += 4){
    float4 w  = *(const float4*)(wr + k);
    float4 p0 = *(const float4*)(Wp + (size_t)k * 2);
    float4 p1 = *(const float4*)(Wp + (size_t)(k + 2) * 2);
    float4 bb = *(const float4*)(bp + k);
    m0 += w.x*p0.x + w.y*p0.z + w.z*p1.x + w.w*p1.z;
    m1 += w.x*p0.y + w.y*p0.w + w.z*p1.y + w.w*p1.w;
    mb += w.x*bb.x + w.y*bb.y + w.z*bb.z + w.w*bb.w;
  }
  M1[(size_t)c*2]   = m0;
  M1[(size_t)c*2+1] = m1;
  bias_e[c] = ebih[c] + ebhh[c] + mb;
  dbias[c]  = dbih[c] + dbhh[c];
}

// -------- E fill: E[b][t][c] = M1[c]·in[b,t] + bias_e[c] --------
__global__ __launch_bounds__(256) void efill(
    const float* __restrict__ inp, const float* __restrict__ M1,
    const float* __restrict__ be, float* __restrict__ E)
{
  size_t i = (size_t)blockIdx.x * 256 + threadIdx.x;
  int c = (int)(i & 2047);
  int t = (int)((i >> 11) & 127);
  int b = (int)(i >> 18);
  float x0 = inp[((size_t)b * S + t) * 2 + 0];
  float x1 = inp[((size_t)b * S + t) * 2 + 1];
  E[i] = M1[(size_t)c*2] * x0 + M1[(size_t)c*2+1] * x1 + be[c];
}

// -------- pack Whh into per-slice contiguous form WP[j][k][g*64+u] --------
__global__ __launch_bounds__(256) void pack_whh(
    const float* __restrict__ Whh, float* __restrict__ WP)
{
  size_t i = (size_t)blockIdx.x * 256 + threadIdx.x;  // 1,048,576
  int p = (int)(i & 255);          // g*64+u
  int k = (int)((i >> 8) & 511);
  int j = (int)(i >> 17);
  int g = p >> 6, u = p & 63;
  int r = g * 512 + j * UPS + u;
  WP[i] = Whh[(size_t)r * H + k];
}

// -------- transpose: out[K][R] = in[R][K] --------
__global__ __launch_bounds__(256) void transpose_k(
    const float* __restrict__ in, float* __restrict__ out, int R, int K)
{
  __shared__ float tile[32][33];
  int r0 = blockIdx.y * 32, k0 = blockIdx.x * 32;
  int tx = threadIdx.x & 31, ty = threadIdx.x >> 5;
  #pragma unroll
  for (int j = 0; j < 4; ++j)
    tile[ty + 8*j][tx] = in[(size_t)(r0 + ty + 8*j) * K + k0 + tx];
  __syncthreads();
  #pragma unroll
  for (int j = 0; j < 4; ++j)
    out[(size_t)(k0 + ty + 8*j) * R + r0 + tx] = tile[tx][ty + 8*j];
}

// -------- generic fp32 GEMM: C = A(MxK) @ B(NxK)^T (+bias) --------
template<int LAYOUT>
__global__ __launch_bounds__(256) void gemm_nt(
    const float* __restrict__ A, const float* __restrict__ Bm,
    const float* __restrict__ bias, float* __restrict__ C,
    int M, int N, int K)
{
  __shared__ float As[16][68];
  __shared__ float Bs[16][68];
  int tid = threadIdx.x;
  int bm = blockIdx.y * 64, bn = blockIdx.x * 64;
  int tm = (tid & 15) * 4, tn = (tid >> 4) * 4;
  float acc[4][4] = {};
  int r  = tid >> 2;
  int kq = (tid & 3) * 4;
  for (int k0 = 0; k0 < K; k0 += 16){
    float4 a = *(const float4*)(A  + (size_t)(bm + r) * K + k0 + kq);
    float4 b = *(const float4*)(Bm + (size_t)(bn + r) * K + k0 + kq);
    __syncthreads();
    As[kq+0][r] = a.x; As[kq+1][r] = a.y; As[kq+2][r] = a.z; As[kq+3][r] = a.w;
    Bs[kq+0][r] = b.x; Bs[kq+1][r] = b.y; Bs[kq+2][r] = b.z; Bs[kq+3][r] = b.w;
    __syncthreads();
    #pragma unroll
    for (int kk = 0; kk < 16; ++kk){
      float4 av = *(const float4*)(&As[kk][tm]);
      float4 bv = *(const float4*)(&Bs[kk][tn]);
      acc[0][0] += av.x*bv.x; acc[0][1] += av.x*bv.y; acc[0][2] += av.x*bv.z; acc[0][3] += av.x*bv.w;
      acc[1][0] += av.y*bv.x; acc[1][1] += av.y*bv.y; acc[1][2] += av.y*bv.z; acc[1][3] += av.y*bv.w;
      acc[2][0] += av.z*bv.x; acc[2][1] += av.z*bv.y; acc[2][2] += av.z*bv.z; acc[2][3] += av.z*bv.w;
      acc[3][0] += av.w*bv.x; acc[3][1] += av.w*bv.y; acc[3][2] += av.w*bv.z; acc[3][3] += av.w*bv.w;
    }
  }
  #pragma unroll
  for (int i = 0; i < 4; ++i){
    int m = bm + tm + i;
    #pragma unroll
    for (int j = 0; j < 4; ++j){
      int n = bn + tn + j;
      float vv = acc[i][j] + (bias ? bias[n] : 0.f);
      if (LAYOUT == 0) C[(size_t)m * N + n] = vv;
      else             C[((size_t)(m >> 7) * 512 + n) * 128 + (m & 127)] = vv;
    }
  }
}

// -------- per-batch-group encoder (r8, proven ~6us/step): grid=256 --------
__global__ __launch_bounds__(256) void encoder_kernel(
    const float* __restrict__ WP,     // [8][512][256]
    const float* __restrict__ E,      // [b][t][2048]
    float* __restrict__ hb,           // [B][2][H] (zeroed)
    float* __restrict__ c_buf,        // [B][H]
    float* __restrict__ enc_out,      // [b][t][h]
    unsigned* __restrict__ htags)     // 256 lines, (b*8+j)*32
{
  __shared__ float hsh[H];
  __shared__ float gpart[4][RPS];
  __shared__ float gfin[4][UPS];
  __shared__ float hloc[UPS];
  const int tid = threadIdx.x, bk = blockIdx.x;
  const int b = bk >> 3, j = bk & 7;
  const int u0 = j * UPS;
  const float* wp = WP + (size_t)j * H * RPS;
  unsigned* myhtags = htags + (size_t)b * 8 * 32;
  const int ph = tid >> 6, c4 = tid & 63;
  float creg = 0.f;
  for (int t = 0; t < S; ++t){
    if (t > 0 && tid < 8){
      while (cloadu(myhtags + tid * 32) < (unsigned)t){}
    }
    __syncthreads();
    { float2 q = cload2(hb + ((size_t)b * 2 + ((t + 1) & 1)) * H + 2 * tid);
      hsh[2*tid] = q.x; hsh[2*tid + 1] = q.y; }
    __syncthreads();
    float4 acc = {0.f, 0.f, 0.f, 0.f};
    const float* wq = wp + ph * RPS + c4 * 4;
    #pragma unroll 4
    for (int kk = 0; kk < 128; ++kk){
      float hv = hsh[4*kk + ph];
      float4 w = *(const float4*)(wq + (size_t)kk * 4 * RPS);
      acc.x = fmaf(w.x, hv, acc.x); acc.y = fmaf(w.y, hv, acc.y);
      acc.z = fmaf(w.z, hv, acc.z); acc.w = fmaf(w.w, hv, acc.w);
    }
    *(float4*)&gpart[ph][c4 * 4] = acc;
    __syncthreads();
    if (tid < 64){
      float4 s0 = *(const float4*)&gpart[0][tid*4];
      float4 s1 = *(const float4*)&gpart[1][tid*4];
      float4 s2 = *(const float4*)&gpart[2][tid*4];
      float4 s3 = *(const float4*)&gpart[3][tid*4];
      int g = tid >> 4, uu = (tid & 15) * 4;
      float4 e = *(const float4*)(E + ((size_t)b * S + t) * G4 + g * 512 + u0 + uu);
      float4 s; s.x = s0.x+s1.x+s2.x+s3.x + e.x; s.y = s0.y+s1.y+s2.y+s3.y + e.y;
      s.z = s0.z+s1.z+s2.z+s3.z + e.z; s.w = s0.w+s1.w+s2.w+s3.w + e.w;
      *(float4*)&gfin[g][uu] = s;
    }
    __syncthreads();
    if (tid < UPS){
      float gi = gfin[0][tid], gf = gfin[1][tid], gg = gfin[2][tid], go = gfin[3][tid];
      creg = sigm(gf) * creg + sigm(gi) * tanh_(gg);
      hloc[tid] = sigm(go) * tanh_(creg);
    }
    __syncthreads();
    if (tid < 32){
      float h0 = hloc[2*tid], h1 = hloc[2*tid + 1];
      cstore2(hb + ((size_t)b * 2 + (t & 1)) * H + u0 + 2*tid, h0, h1);
      *(float2*)(enc_out + ((size_t)b * S + t) * H + u0 + 2*tid) = make_float2(h0, h1);
    }
    __syncthreads();   // drain publishes before tag
    if (tid == 0) cstoreu(myhtags + j * 32, (unsigned)(t + 1));
  }
  if (tid < UPS) c_buf[(size_t)b * H + u0 + tid] = creg;
}

// -------- decoder: owner-centric 2-hop pipeline, grid=416 --------
// y-blocks [0,256): b=bk>>3, j=bk&7. step t: poll htag>=t+1; stage h(t-1)
//   (parity t&1); y-slice = Whh_slice@h; publish ybuf + wtag[b*12+j]=t+1.
// score-blocks [256,384): b=(bk-256)>>2, q=(bk-256)&3. iter tau: poll
//   htag>=tau+2; stage h(tau); dp-slice (local only); ps(tau)[s] partials;
//   publish psbuf + wtag[b*12+8+q]=tau+1.
// owner [384,416): b=bk-384. holds c, top, scores. step t: [t>=1: poll score
//   wtags>=t; sum ps(t-1); argmax -> top local]; D-row; poll y wtags>=t+1;
//   stage y(t); pointwise; publish h(t) parity (t+1)&1, htag=t+2; THEN
//   softmax+out row t-1 (off-path). Epilogue: ps(127) -> out row 127.
// Single-buffer ybuf/psbuf safety: writer's htag-gate implies owner staged
// the previous value (stage precedes htag store, drained by __syncthreads).
// h ping-pong safety: owner writes h(t) over h(t-2) only after all wtags
// >= t (workers staged h(t-2) before those publishes).
__global__ __launch_bounds__(256) void decoder_kernel(
    const float* __restrict__ WP,     // [8][512][256] packed dec Whh
    const float* __restrict__ D,      // [b][t][2048]
    const float* __restrict__ dbias,  // [2048]
    const float* __restrict__ W2T,    // [512][512]
    const float* __restrict__ Pt,     // [b][h][s]
    const float* __restrict__ vvec,   // [512]
    const float* __restrict__ c_buf,  // [B][H]
    const float* __restrict__ enc_out,// [b][t][h]
    float* __restrict__ hb,           // [B][2][H]
    float* __restrict__ ybuf,         // [B][2048]
    float* __restrict__ psbuf,        // [B][4][128]
    unsigned* __restrict__ htag,      // 32 lines
    unsigned* __restrict__ wtags,     // 384 lines
    float* __restrict__ out)          // [b][t][s]
{
  const int tid = threadIdx.x, bk = blockIdx.x;
  if (bk < 256){
    // =================== y role ===================
    __shared__ float hsh[H];
    __shared__ float gpart[4][RPS];
    const int b = bk >> 3, j = bk & 7;
    const float* wp = WP + (size_t)j * H * RPS;
    const unsigned* myh = htag + (size_t)b * 32;
    unsigned* mytag = wtags + (size_t)(b * 12 + j) * 32;
    const int ph = tid >> 6, c4 = tid & 63;
    for (int t = 0; t < S; ++t){
      if (tid == 0){
        while (cloadu(myh) < (unsigned)(t + 1)) __builtin_amdgcn_s_sleep(1);
      }
      __syncthreads();
      { float2 q = cload2(hb + ((size_t)b * 2 + (t & 1)) * H + 2 * tid);
        hsh[2*tid] = q.x; hsh[2*tid + 1] = q.y; }
      __syncthreads();
      float4 acc = {0.f, 0.f, 0.f, 0.f};
      const float* wq = wp + ph * RPS + c4 * 4;
      #pragma unroll 4
      for (int kk = 0; kk < 128; ++kk){
        float hv = hsh[4*kk + ph];
        float4 w = *(const float4*)(wq + (size_t)kk * 4 * RPS);
        acc.x = fmaf(w.x, hv, acc.x); acc.y = fmaf(w.y, hv, acc.y);
        acc.z = fmaf(w.z, hv, acc.z); acc.w = fmaf(w.w, hv, acc.w);
      }
      *(float4*)&gpart[ph][c4 * 4] = acc;
      __syncthreads();
      if (tid < 64){
        float4 s0 = *(const float4*)&gpart[0][tid*4];
        float4 s1 = *(const float4*)&gpart[1][tid*4];
        float4 s2 = *(const float4*)&gpart[2][tid*4];
        float4 s3 = *(const float4*)&gpart[3][tid*4];
        float a0 = s0.x+s1.x+s2.x+s3.x;
        float a1 = s0.y+s1.y+s2.y+s3.y;
        float a2 = s0.z+s1.z+s2.z+s3.z;
        float a3 = s0.w+s1.w+s2.w+s3.w;
        float* dst = ybuf + (size_t)b * G4 + j * 256 + tid * 4;
        cstore2(dst, a0, a1);
        cstore2(dst + 2, a2, a3);
      }
      __syncthreads();   // drain y publish before tag
      if (tid == 0) cstoreu(mytag, (unsigned)(t + 1));
    }
  } else if (bk < 384){
    // =================== score role ===================
    __shared__ float hsh[H];
    __shared__ float dps[2][128];
    __shared__ float dpl[128];
    __shared__ float vsh2[128];
    __shared__ float pspart[2][128];
    const int b = (bk - 256) >> 2, q = (bk - 256) & 3;
    const unsigned* myh = htag + (size_t)b * 32;
    unsigned* mytag = wtags + (size_t)(b * 12 + 8 + q) * 32;
    if (tid < 128) vsh2[tid] = vvec[q * 128 + tid];
    for (int tau = 0; tau < S; ++tau){
      if (tid == 0){
        while (cloadu(myh) < (unsigned)(tau + 2)) __builtin_amdgcn_s_sleep(1);
      }
      __syncthreads();
      { float2 qq = cload2(hb + ((size_t)b * 2 + ((tau + 1) & 1)) * H + 2 * tid);
        hsh[2*tid] = qq.x; hsh[2*tid + 1] = qq.y; }
      __syncthreads();
      // dp-slice: cols q*128+nl; halves over k
      {
        int nl = tid & 127, kh = tid >> 7;
        const float* w = W2T + (size_t)(kh * 256) * H + q * 128 + nl;
        float a = 0.f;
        #pragma unroll 8
        for (int k2 = 0; k2 < 256; ++k2)
          a = fmaf(w[(size_t)k2 * H], hsh[kh * 256 + k2], a);
        dps[kh][nl] = a;
      }
      __syncthreads();
      if (tid < 128) dpl[tid] = dps[0][tid] + dps[1][tid];
      __syncthreads();
      // partial scores over this 128-unit slice
      {
        int s = tid & 127, nh = tid >> 7;
        const float* Pp = Pt + ((size_t)b * H + q * 128 + nh * 64) * S + s;
        float cs = 0.f;
        #pragma unroll 4
        for (int n = 0; n < 64; ++n){
          float x = Pp[(size_t)n * S] + dpl[nh * 64 + n];
          cs = fmaf(vsh2[nh * 64 + n], tanh_(x), cs);
        }
        pspart[nh][s] = cs;
      }
      __syncthreads();
      if (tid < 64)
        cstore2(psbuf + ((size_t)b * 4 + q) * 128 + 2 * tid,
                pspart[0][2*tid] + pspart[1][2*tid],
                pspart[0][2*tid+1] + pspart[1][2*tid+1]);
      __syncthreads();   // drain ps publish before tag
      if (tid == 0) cstoreu(mytag, (unsigned)(tau + 1));
    }
  } else {
    // =================== owner role ===================
    __shared__ float ysh[G4];
    __shared__ float hloc[H];
    __shared__ float wm[2]; __shared__ int wi[2]; __shared__ float wsum[2];
    const int b = bk - 384;
    const unsigned* yt = wtags + (size_t)b * 12 * 32;
    unsigned* myh = htag + (size_t)b * 32;
    float c0 = c_buf[(size_t)b * H + tid];
    float c1 = c_buf[(size_t)b * H + 256 + tid];
    // publish h(-1) = enc h(127), parity 0
    { float2 hv = *(const float2*)(enc_out + ((size_t)b * S + (S - 1)) * H + 2 * tid);
      cstore2(hb + (size_t)b * 2 * H + 2 * tid, hv.x, hv.y); }
    __syncthreads();
    if (tid == 0) cstoreu(myh, 1u);
    float sc = 0.f, mglob = 0.f;
    for (int t = 0; t < S; ++t){
      int am = 0;
      if (t >= 1){
        if (tid < 4){
          const unsigned* L = yt + (size_t)(8 + tid) * 32;
          while (cloadu(L) < (unsigned)t) __builtin_amdgcn_s_sleep(1);
        }
        __syncthreads();
        if (tid < 128){
          const float* pp = psbuf + (size_t)b * 512 + tid;
          sc = cloadf(pp) + cloadf(pp + 128) + cloadf(pp + 256) + cloadf(pp + 384);
          float mv = sc; int mi = tid;
          #pragma unroll
          for (int off = 32; off > 0; off >>= 1){
            float ov = __shfl_xor(mv, off, 64);
            int   oi = __shfl_xor(mi, off, 64);
            if (ov > mv || (ov == mv && oi < mi)){ mv = ov; mi = oi; }
          }
          if ((tid & 63) == 0){ wm[tid >> 6] = mv; wi[tid >> 6] = mi; }
        }
        __syncthreads();
        { float m0 = wm[0], m1 = wm[1];
          if (m1 > m0 || (m1 == m0 && wi[1] < wi[0])){ mglob = m1; am = wi[1]; }
          else { mglob = m0; am = wi[0]; } }
      }
      const float* xr = (t == 0) ? dbias : D + ((size_t)b * S + am) * G4;
      // prefetch x-row (cached loads; hides under y wait)
      float x0 = xr[tid],        x1 = xr[512 + tid],
            x2 = xr[1024 + tid], x3 = xr[1536 + tid];
      int u2 = tid + 256;
      float x4 = xr[u2],         x5 = xr[512 + u2],
            x6 = xr[1024 + u2],  x7 = xr[1536 + u2];
      if (tid < 8){
        const unsigned* L = yt + (size_t)tid * 32;
        while (cloadu(L) < (unsigned)(t + 1)) __builtin_amdgcn_s_sleep(1);
      }
      __syncthreads();
      #pragma unroll
      for (int r = 0; r < 4; ++r){
        float2 q2 = cload2(ybuf + (size_t)b * G4 + r * 512 + 2 * tid);
        ysh[r * 512 + 2 * tid] = q2.x; ysh[r * 512 + 2 * tid + 1] = q2.y;
      }
      __syncthreads();
      {
        int j0 = tid >> 6, uu0 = tid & 63;
        float gi = ysh[j0*256 +       uu0] + x0;
        float gf = ysh[j0*256 +  64 + uu0] + x1;
        float gg = ysh[j0*256 + 128 + uu0] + x2;
        float go = ysh[j0*256 + 192 + uu0] + x3;
        c0 = sigm(gf) * c0 + sigm(gi) * tanh_(gg);
        hloc[tid] = sigm(go) * tanh_(c0);
        int j1 = u2 >> 6, uu1 = u2 & 63;
        gi = ysh[j1*256 +       uu1] + x4;
        gf = ysh[j1*256 +  64 + uu1] + x5;
        gg = ysh[j1*256 + 128 + uu1] + x6;
        go = ysh[j1*256 + 192 + uu1] + x7;
        c1 = sigm(gf) * c1 + sigm(gi) * tanh_(gg);
        hloc[u2] = sigm(go) * tanh_(c1);
      }
      __syncthreads();
      cstore2(hb + ((size_t)b * 2 + ((t + 1) & 1)) * H + 2 * tid,
              hloc[2*tid], hloc[2*tid + 1]);
      __syncthreads();   // drain h publish before tag
      if (tid == 0) cstoreu(myh, (unsigned)(t + 2));
      // off-path: out row t-1
      if (t >= 1){
        if (tid < 128){
          float se = __expf(sc - mglob);
          float ss = se;
          #pragma unroll
          for (int off = 32; off > 0; off >>= 1) ss += __shfl_xor(ss, off, 64);
          if ((tid & 63) == 0) wsum[tid >> 6] = ss;
        }
        __syncthreads();
        if (tid < 128){
          float lse = __logf(wsum[0] + wsum[1]);
          out[((size_t)b * S + (t - 1)) * S + tid] = sc - mglob - lse;
        }
      }
    }
    // epilogue: out row 127 from ps(127)
    if (tid < 4){
      const unsigned* L = yt + (size_t)(8 + tid) * 32;
      while (cloadu(L) < (unsigned)S) __builtin_amdgcn_s_sleep(1);
    }
    __syncthreads();
    if (tid < 128){
      const float* pp = psbuf + (size_t)b * 512 + tid;
      sc = cloadf(pp) + cloadf(pp + 128) + cloadf(pp + 256) + cloadf(pp + 384);
      float mv = sc; int mi = tid;
      #pragma unroll
      for (int off = 32; off > 0; off >>= 1){
        float ov = __shfl_xor(mv, off, 64);
        int   oi = __shfl_xor(mi, off, 64);
        if (ov > mv || (ov == mv && oi < mi)){ mv = ov; mi = oi; }
      }
      if ((tid & 63) == 0){ wm[tid >> 6] = mv; wi[tid >> 6] = mi; }
    }
    __syncthreads();
    { float m0 = wm[0], m1 = wm[1];
      mglob = (m1 > m0 || (m1 == m0 && wi[1] < wi[0])) ? m1 : m0; }
    if (tid < 128){
      float se = __expf(sc - mglob);
      float ss = se;
      #pragma unroll
      for (int off = 32; off > 0; off >>= 1) ss += __shfl_xor(ss, off, 64);
      if ((tid & 63) == 0) wsum[tid >> 6] = ss;
    }
    __syncthreads();
    if (tid < 128){
      float lse = __logf(wsum[0] + wsum[1]);
      out[((size_t)b * S + (S - 1)) * S + tid] = sc - mglob - lse;
    }
  }
}

extern "C" void kernel_launch(void* const* d_in, const int* in_sizes, int n_in,
                              void* d_out, int out_size, void* d_ws, size_t ws_size,
                              hipStream_t stream) {
  const float* inputs  = (const float*)d_in[0];
  const float* Wp      = (const float*)d_in[1];
  const float* bp      = (const float*)d_in[2];
  const float* eWih    = (const float*)d_in[3];
  const float* eWhh    = (const float*)d_in[4];
  const float* ebih    = (const float*)d_in[5];
  const float* ebhh    = (const float*)d_in[6];
  const float* dWih    = (const float*)d_in[7];
  const float* dWhh    = (const float*)d_in[8];
  const float* dbih    = (const float*)d_in[9];
  const float* dbhh    = (const float*)d_in[10];
  const float* W1      = (const float*)d_in[11];
  const float* W2      = (const float*)d_in[12];
  const float* v       = (const float*)d_in[13];
  float* out = (float*)d_out;

  float* ws = (float*)d_ws;
  float* E       = ws + OFF_E;    // reused as D after encoder
  float* enc_out = ws + OFF_EO;
  float* Pt      = ws + OFF_PT;
  float* WPe     = ws + OFF_WPE;
  float* WPd     = ws + OFF_WPD;
  float* W2T     = ws + OFF_W2T;
  float* hb      = ws + OFF_HB;
  float* c_buf   = ws + OFF_CB;
  float* ybuf    = ws + OFF_YB;
  float* psbuf   = ws + OFF_PS;
  float* M1      = ws + OFF_M1;
  float* bias_e  = ws + OFF_BE;
  float* dbias   = ws + OFF_DB;
  unsigned* enc_htags = (unsigned*)(ws + OFF_END);
  unsigned* dec_htag  = enc_htags + 256 * 32;
  unsigned* wtags     = dec_htag + 32 * 32;

  // deterministic per launch: zero h buffers + all tag lines
  hipMemsetAsync(hb, 0, (size_t)B * 2 * H * sizeof(float), stream);
  hipMemsetAsync(enc_htags, 0, CTRL_U32 * sizeof(unsigned), stream);

  prep_misc<<<G4 / 256, 256, 0, stream>>>(eWih, Wp, bp, ebih, ebhh, dbih, dbhh,
                                          M1, bias_e, dbias);
  efill<<<(int)(SZ_E / 256), 256, 0, stream>>>(inputs, M1, bias_e, E);
  pack_whh<<<(int)(SZ_WP / 256), 256, 0, stream>>>(eWhh, WPe);
  pack_whh<<<(int)(SZ_WP / 256), 256, 0, stream>>>(dWhh, WPd);
  { dim3 g(H / 32, H / 32); transpose_k<<<g, 256, 0, stream>>>(W2, W2T, H, H); }

  encoder_kernel<<<256, 256, 0, stream>>>(WPe, E, hb, c_buf, enc_out, enc_htags);

  // D = enc_out @ dWih^T + dbias (into E's buffer; encoder is done with E)
  float* D = E;
  { dim3 grid(G4 / 64, (B * S) / 64);
    gemm_nt<0><<<grid, 256, 0, stream>>>(enc_out, dWih, dbias, D, B * S, G4, H); }
  { dim3 grid(H / 64, (B * S) / 64);
    gemm_nt<1><<<grid, 256, 0, stream>>>(enc_out, W1, nullptr, Pt, B * S, H, H); }

  decoder_kernel<<<416, 256, 0, stream>>>(WPd, D, dbias, W2T, Pt, v, c_buf,
                                          enc_out, hb, ybuf, psbuf,
                                          dec_htag, wtags, out);
  (void)in_sizes; (void)n_in; (void)out_size; (void)ws_size;
}

// Round 10
// 2959.296 us; speedup vs baseline: 2.8929x; 1.0713x over previous
//
#include <hip/hip_runtime.h>
#include <math.h>

// Problem constants
static constexpr int H   = 512;
static constexpr int B   = 32;
static constexpr int S   = 128;
static constexpr int G4  = 2048;  // 4*H
static constexpr int UPS = 64;    // units per y-slice
static constexpr int RPS = 256;   // rows per y-slice (4 gates * UPS)
static constexpr int NSL = 8;     // y-slices per batch

// ws layout (floats)
static constexpr size_t OFF_E   = 0;                          // E [b][t][c]; reused as D
static constexpr size_t SZ_E    = (size_t)B * S * G4;         // 8,388,608
static constexpr size_t OFF_EO  = OFF_E + SZ_E;               // enc_out [b][t][h]
static constexpr size_t SZ_EO   = (size_t)B * S * H;
static constexpr size_t OFF_PT  = OFF_EO + SZ_EO;             // P_t [b][h][s]
static constexpr size_t SZ_PT   = (size_t)B * H * S;
static constexpr size_t OFF_WPE = OFF_PT + SZ_PT;             // packed enc Whh [8][512][256]
static constexpr size_t SZ_WP   = (size_t)NSL * H * RPS;      // 1,048,576
static constexpr size_t OFF_WPD = OFF_WPE + SZ_WP;            // packed dec Whh
static constexpr size_t OFF_W2T = OFF_WPD + SZ_WP;            // W2T [512][512]
static constexpr size_t OFF_HB  = OFF_W2T + (size_t)H * H;    // hb [B][2][H]
static constexpr size_t OFF_CB  = OFF_HB + (size_t)B * 2 * H; // c_buf [B][H]
static constexpr size_t OFF_PS  = OFF_CB + (size_t)B * H;     // psbuf [B][4][128]
static constexpr size_t OFF_M1  = OFF_PS + (size_t)B * 512;
static constexpr size_t OFF_BE  = OFF_M1 + (size_t)G4 * 2;
static constexpr size_t OFF_DB  = OFF_BE + G4;
static constexpr size_t OFF_END = OFF_DB + G4;
// u32 ctrl at OFF_END: enc_htags[256], dec_htags[256], pstags[128], tops[32] (x32 lines)
static constexpr int CTRL_U32 = (256 + 256 + 128 + 32) * 32;

__device__ __forceinline__ float sigm(float x){
  float e = __expf(-x);
  return 1.0f / (1.0f + e);
}
__device__ __forceinline__ float tanh_(float x){
  float e = __expf(2.0f * x);
  return 1.0f - 2.0f / (1.0f + e);
}

// agent-scope (coherence-point) accessors; discipline: __syncthreads (vmcnt
// drain) between data stores/loads and the tag store (validated r2-r9)
__device__ __forceinline__ float cloadf(const float* p){
  union { unsigned u; float f; } c;
  c.u = __hip_atomic_load((const unsigned*)p, __ATOMIC_RELAXED,
                          __HIP_MEMORY_SCOPE_AGENT);
  return c.f;
}
__device__ __forceinline__ float2 cload2(const float* p){
  union { unsigned long long u; float2 f; } c;
  c.u = __hip_atomic_load((const unsigned long long*)p, __ATOMIC_RELAXED,
                          __HIP_MEMORY_SCOPE_AGENT);
  return c.f;
}
__device__ __forceinline__ void cstore2(float* p, float a, float b){
  union { unsigned long long u; float2 f; } c;
  c.f = make_float2(a, b);
  __hip_atomic_store((unsigned long long*)p, c.u, __ATOMIC_RELAXED,
                     __HIP_MEMORY_SCOPE_AGENT);
}
__device__ __forceinline__ unsigned cloadu(const unsigned* p){
  return __hip_atomic_load(p, __ATOMIC_RELAXED, __HIP_MEMORY_SCOPE_AGENT);
}
__device__ __forceinline__ void cstoreu(unsigned* p, unsigned v){
  __hip_atomic_store(p, v, __ATOMIC_RELAXED, __HIP_MEMORY_SCOPE_AGENT);
}

// -------- prep: M1 = Wih@Wp, bias_e = Wih@bp + bih + bhh, dbias --------
__global__ __launch_bounds__(256) void prep_misc(
    const float* __restrict__ eWih, const float* __restrict__ Wp,
    const float* __restrict__ bp,  const float* __restrict__ ebih,
    const float* __restrict__ ebhh, const float* __restrict__ dbih,
    const float* __restrict__ dbhh,
    float* __restrict__ M1, float* __restrict__ bias_e, float* __restrict__ dbias)
{
  int c = blockIdx.x * 256 + threadIdx.x;   // 0..2047
  const float* wr = eWih + (size_t)c * H;
  float m0 = 0.f, m1 = 0.f, mb = 0.f;
  for (int k = 0; k < H; k += 4){
    float4 w  = *(const float4*)(wr + k);
    float4 p0 = *(const float4*)(Wp + (size_t)k * 2);
    float4 p1 = *(const float4*)(Wp + (size_t)(k + 2) * 2);
    float4 bb = *(const float4*)(bp + k);
    m0 += w.x*p0.x + w.y*p0.z + w.z*p1.x + w.w*p1.z;
    m1 += w.x*p0.y + w.y*p0.w + w.z*p1.y + w.w*p1.w;
    mb += w.x*bb.x + w.y*bb.y + w.z*bb.z + w.w*bb.w;
  }
  M1[(size_t)c*2]   = m0;
  M1[(size_t)c*2+1] = m1;
  bias_e[c] = ebih[c] + ebhh[c] + mb;
  dbias[c]  = dbih[c] + dbhh[c];
}

// -------- E fill: E[b][t][c] = M1[c]·in[b,t] + bias_e[c] --------
__global__ __launch_bounds__(256) void efill(
    const float* __restrict__ inp, const float* __restrict__ M1,
    const float* __restrict__ be, float* __restrict__ E)
{
  size_t i = (size_t)blockIdx.x * 256 + threadIdx.x;
  int c = (int)(i & 2047);
  int t = (int)((i >> 11) & 127);
  int b = (int)(i >> 18);
  float x0 = inp[((size_t)b * S + t) * 2 + 0];
  float x1 = inp[((size_t)b * S + t) * 2 + 1];
  E[i] = M1[(size_t)c*2] * x0 + M1[(size_t)c*2+1] * x1 + be[c];
}

// -------- pack Whh into per-slice contiguous form WP[j][k][g*64+u] --------
__global__ __launch_bounds__(256) void pack_whh(
    const float* __restrict__ Whh, float* __restrict__ WP)
{
  size_t i = (size_t)blockIdx.x * 256 + threadIdx.x;  // 1,048,576
  int p = (int)(i & 255);          // g*64+u
  int k = (int)((i >> 8) & 511);
  int j = (int)(i >> 17);
  int g = p >> 6, u = p & 63;
  int r = g * 512 + j * UPS + u;
  WP[i] = Whh[(size_t)r * H + k];
}

// -------- transpose: out[K][R] = in[R][K] --------
__global__ __launch_bounds__(256) void transpose_k(
    const float* __restrict__ in, float* __restrict__ out, int R, int K)
{
  __shared__ float tile[32][33];
  int r0 = blockIdx.y * 32, k0 = blockIdx.x * 32;
  int tx = threadIdx.x & 31, ty = threadIdx.x >> 5;
  #pragma unroll
  for (int j = 0; j < 4; ++j)
    tile[ty + 8*j][tx] = in[(size_t)(r0 + ty + 8*j) * K + k0 + tx];
  __syncthreads();
  #pragma unroll
  for (int j = 0; j < 4; ++j)
    out[(size_t)(k0 + ty + 8*j) * R + r0 + tx] = tile[tx][ty + 8*j];
}

// -------- generic fp32 GEMM: C = A(MxK) @ B(NxK)^T (+bias) --------
template<int LAYOUT>
__global__ __launch_bounds__(256) void gemm_nt(
    const float* __restrict__ A, const float* __restrict__ Bm,
    const float* __restrict__ bias, float* __restrict__ C,
    int M, int N, int K)
{
  __shared__ float As[16][68];
  __shared__ float Bs[16][68];
  int tid = threadIdx.x;
  int bm = blockIdx.y * 64, bn = blockIdx.x * 64;
  int tm = (tid & 15) * 4, tn = (tid >> 4) * 4;
  float acc[4][4] = {};
  int r  = tid >> 2;
  int kq = (tid & 3) * 4;
  for (int k0 = 0; k0 < K; k0 += 16){
    float4 a = *(const float4*)(A  + (size_t)(bm + r) * K + k0 + kq);
    float4 b = *(const float4*)(Bm + (size_t)(bn + r) * K + k0 + kq);
    __syncthreads();
    As[kq+0][r] = a.x; As[kq+1][r] = a.y; As[kq+2][r] = a.z; As[kq+3][r] = a.w;
    Bs[kq+0][r] = b.x; Bs[kq+1][r] = b.y; Bs[kq+2][r] = b.z; Bs[kq+3][r] = b.w;
    __syncthreads();
    #pragma unroll
    for (int kk = 0; kk < 16; ++kk){
      float4 av = *(const float4*)(&As[kk][tm]);
      float4 bv = *(const float4*)(&Bs[kk][tn]);
      acc[0][0] += av.x*bv.x; acc[0][1] += av.x*bv.y; acc[0][2] += av.x*bv.z; acc[0][3] += av.x*bv.w;
      acc[1][0] += av.y*bv.x; acc[1][1] += av.y*bv.y; acc[1][2] += av.y*bv.z; acc[1][3] += av.y*bv.w;
      acc[2][0] += av.z*bv.x; acc[2][1] += av.z*bv.y; acc[2][2] += av.z*bv.z; acc[2][3] += av.z*bv.w;
      acc[3][0] += av.w*bv.x; acc[3][1] += av.w*bv.y; acc[3][2] += av.w*bv.z; acc[3][3] += av.w*bv.w;
    }
  }
  #pragma unroll
  for (int i = 0; i < 4; ++i){
    int m = bm + tm + i;
    #pragma unroll
    for (int j = 0; j < 4; ++j){
      int n = bn + tn + j;
      float vv = acc[i][j] + (bias ? bias[n] : 0.f);
      if (LAYOUT == 0) C[(size_t)m * N + n] = vv;
      else             C[((size_t)(m >> 7) * 512 + n) * 128 + (m & 127)] = vv;
    }
  }
}

// -------- per-batch-group encoder (r8, proven ~6us/step): grid=256 --------
__global__ __launch_bounds__(256) void encoder_kernel(
    const float* __restrict__ WP,     // [8][512][256]
    const float* __restrict__ E,      // [b][t][2048]
    float* __restrict__ hb,           // [B][2][H] (zeroed)
    float* __restrict__ c_buf,        // [B][H]
    float* __restrict__ enc_out,      // [b][t][h]
    unsigned* __restrict__ htags)     // 256 lines, (b*8+j)*32
{
  __shared__ float hsh[H];
  __shared__ float gpart[4][RPS];
  __shared__ float gfin[4][UPS];
  __shared__ float hloc[UPS];
  const int tid = threadIdx.x, bk = blockIdx.x;
  const int b = bk >> 3, j = bk & 7;
  const int u0 = j * UPS;
  const float* wp = WP + (size_t)j * H * RPS;
  unsigned* myhtags = htags + (size_t)b * 8 * 32;
  const int ph = tid >> 6, c4 = tid & 63;
  float creg = 0.f;
  for (int t = 0; t < S; ++t){
    if (t > 0 && tid < 8){
      while (cloadu(myhtags + tid * 32) < (unsigned)t){}
    }
    __syncthreads();
    { float2 q = cload2(hb + ((size_t)b * 2 + ((t + 1) & 1)) * H + 2 * tid);
      hsh[2*tid] = q.x; hsh[2*tid + 1] = q.y; }
    __syncthreads();
    float4 acc = {0.f, 0.f, 0.f, 0.f};
    const float* wq = wp + ph * RPS + c4 * 4;
    #pragma unroll 4
    for (int kk = 0; kk < 128; ++kk){
      float hv = hsh[4*kk + ph];
      float4 w = *(const float4*)(wq + (size_t)kk * 4 * RPS);
      acc.x = fmaf(w.x, hv, acc.x); acc.y = fmaf(w.y, hv, acc.y);
      acc.z = fmaf(w.z, hv, acc.z); acc.w = fmaf(w.w, hv, acc.w);
    }
    *(float4*)&gpart[ph][c4 * 4] = acc;
    __syncthreads();
    if (tid < 64){
      float4 s0 = *(const float4*)&gpart[0][tid*4];
      float4 s1 = *(const float4*)&gpart[1][tid*4];
      float4 s2 = *(const float4*)&gpart[2][tid*4];
      float4 s3 = *(const float4*)&gpart[3][tid*4];
      int g = tid >> 4, uu = (tid & 15) * 4;
      float4 e = *(const float4*)(E + ((size_t)b * S + t) * G4 + g * 512 + u0 + uu);
      float4 s; s.x = s0.x+s1.x+s2.x+s3.x + e.x; s.y = s0.y+s1.y+s2.y+s3.y + e.y;
      s.z = s0.z+s1.z+s2.z+s3.z + e.z; s.w = s0.w+s1.w+s2.w+s3.w + e.w;
      *(float4*)&gfin[g][uu] = s;
    }
    __syncthreads();
    if (tid < UPS){
      float gi = gfin[0][tid], gf = gfin[1][tid], gg = gfin[2][tid], go = gfin[3][tid];
      creg = sigm(gf) * creg + sigm(gi) * tanh_(gg);
      hloc[tid] = sigm(go) * tanh_(creg);
    }
    __syncthreads();
    if (tid < 32){
      float h0 = hloc[2*tid], h1 = hloc[2*tid + 1];
      cstore2(hb + ((size_t)b * 2 + (t & 1)) * H + u0 + 2*tid, h0, h1);
      *(float2*)(enc_out + ((size_t)b * S + t) * H + u0 + 2*tid) = make_float2(h0, h1);
    }
    __syncthreads();   // drain publishes before tag
    if (tid == 0) cstoreu(myhtags + j * 32, (unsigned)(t + 1));
  }
  if (tid < UPS) c_buf[(size_t)b * H + u0 + tid] = creg;
}

// -------- decoder: 1-hop h-cycle, grid=416 --------
// Tags: htag[b*8+j] = t+2 <=> h(t) slice j published (parity t&1); init value 1
//   <=> h(-1) at parity 1 (from enc_out[127], published by each y-block).
// y-blocks [0,256): b=bk>>3, j=bk&7, own c-state for 64 units. Step t: poll 8
//   htags>=t+1; stage h(t-1) [parity (t+1)&1]; gates gemv; poll top(t-1)
//   (epoch t; hidden behind gemv); x-term = D[b][top] or dbias; pointwise;
//   publish h(t) slice [parity t&1]; htag=t+2.
// score-blocks [256,384): b=(bk-256)>>2, q=(bk-256)&3. Iter tau: poll htags
//   >=tau+2; stage h(tau); dp-slice (block-local); ps(tau) partial scores;
//   publish psbuf[b][q]; pstag=tau+1.
// owner [384,416): b=bk-384. Step t: poll 4 pstags>=t+1; sum ps(t); argmax;
//   publish toptag=((t+1)<<8)|idx; then softmax + out row t (off-path).
// Safety: (1) hb ping-pong: y writes h(t) over h(t-2) after htags>=t+1 and
//   top(t-1); top(t-1) implies owner read ps(t-2)... full chain: top(t-1)
//   needs ps(t-1) (score staged h(t-1), hence finished staging h(t-2));
//   htags>=t+1 implies all y staged h(t-1) (and earlier h(t-2)). (2) psbuf
//   single-buffer: score overwrites ps(tau) at iter tau+1 gated by htags
//   >=tau+3 -> y published h(tau+1) -> y saw top(tau) -> owner read ps(tau).
__global__ __launch_bounds__(256) void decoder_kernel(
    const float* __restrict__ WP,     // [8][512][256] packed dec Whh
    const float* __restrict__ D,      // [b][t][2048]
    const float* __restrict__ dbias,  // [2048]
    const float* __restrict__ W2T,    // [512][512]
    const float* __restrict__ Pt,     // [b][h][s]
    const float* __restrict__ vvec,   // [512]
    const float* __restrict__ c_buf,  // [B][H]
    const float* __restrict__ enc_out,// [b][t][h]
    float* __restrict__ hb,           // [B][2][H]
    float* __restrict__ psbuf,        // [B][4][128]
    unsigned* __restrict__ htags,     // 256 lines
    unsigned* __restrict__ pstags,    // 128 lines
    unsigned* __restrict__ tops,      // 32 lines, (epoch<<8)|idx
    float* __restrict__ out)          // [b][t][s]
{
  const int tid = threadIdx.x, bk = blockIdx.x;
  if (bk < 256){
    // =================== y role (gemv + pointwise) ===================
    __shared__ float hsh[H];
    __shared__ float gpart[4][RPS];
    __shared__ float gfin[4][UPS];
    __shared__ float hloc[UPS];
    __shared__ int   topsh;
    const int b = bk >> 3, j = bk & 7;
    const int u0 = j * UPS;
    const float* wp = WP + (size_t)j * H * RPS;
    unsigned* myhtags = htags + (size_t)b * 8 * 32;
    const unsigned* mytop = tops + (size_t)b * 32;
    const int ph = tid >> 6, c4 = tid & 63;
    float creg = (tid < UPS) ? c_buf[(size_t)b * H + u0 + tid] : 0.f;
    // init: publish h(-1) slice (enc h(127)) at parity 1
    if (tid < 32){
      float2 hv = *(const float2*)(enc_out + ((size_t)b * S + (S-1)) * H + u0 + 2*tid);
      cstore2(hb + ((size_t)b * 2 + 1) * H + u0 + 2*tid, hv.x, hv.y);
    }
    __syncthreads();   // drain init publish before tag
    if (tid == 0) cstoreu(myhtags + j * 32, 1u);
    for (int t = 0; t < S; ++t){
      if (tid < 8){
        while (cloadu(myhtags + tid * 32) < (unsigned)(t + 1)) __builtin_amdgcn_s_sleep(1);
      }
      __syncthreads();
      { float2 q = cload2(hb + ((size_t)b * 2 + ((t + 1) & 1)) * H + 2 * tid);
        hsh[2*tid] = q.x; hsh[2*tid + 1] = q.y; }
      __syncthreads();
      float4 acc = {0.f, 0.f, 0.f, 0.f};
      const float* wq = wp + ph * RPS + c4 * 4;
      #pragma unroll 4
      for (int kk = 0; kk < 128; ++kk){
        float hv = hsh[4*kk + ph];
        float4 w = *(const float4*)(wq + (size_t)kk * 4 * RPS);
        acc.x = fmaf(w.x, hv, acc.x); acc.y = fmaf(w.y, hv, acc.y);
        acc.z = fmaf(w.z, hv, acc.z); acc.w = fmaf(w.w, hv, acc.w);
      }
      *(float4*)&gpart[ph][c4 * 4] = acc;
      // poll top(t-1) (mostly ready by gemv end)
      if (t > 0 && tid == 0){
        unsigned vt;
        do { vt = cloadu(mytop); } while ((vt >> 8) != (unsigned)t);
        topsh = (int)(vt & 255u);
      }
      __syncthreads();
      if (tid < 64){
        float4 s0 = *(const float4*)&gpart[0][tid*4];
        float4 s1 = *(const float4*)&gpart[1][tid*4];
        float4 s2 = *(const float4*)&gpart[2][tid*4];
        float4 s3 = *(const float4*)&gpart[3][tid*4];
        int g = tid >> 4, uu = (tid & 15) * 4;
        const float* xr = (t == 0) ? dbias : D + ((size_t)b * S + topsh) * G4;
        float4 e = *(const float4*)(xr + g * 512 + u0 + uu);
        float4 s; s.x = s0.x+s1.x+s2.x+s3.x + e.x; s.y = s0.y+s1.y+s2.y+s3.y + e.y;
        s.z = s0.z+s1.z+s2.z+s3.z + e.z; s.w = s0.w+s1.w+s2.w+s3.w + e.w;
        *(float4*)&gfin[g][uu] = s;
      }
      __syncthreads();
      if (tid < UPS){
        float gi = gfin[0][tid], gf = gfin[1][tid], gg = gfin[2][tid], go = gfin[3][tid];
        creg = sigm(gf) * creg + sigm(gi) * tanh_(gg);
        hloc[tid] = sigm(go) * tanh_(creg);
      }
      __syncthreads();
      if (tid < 32)
        cstore2(hb + ((size_t)b * 2 + (t & 1)) * H + u0 + 2*tid,
                hloc[2*tid], hloc[2*tid + 1]);
      __syncthreads();   // drain h publish before tag
      if (tid == 0) cstoreu(myhtags + j * 32, (unsigned)(t + 2));
    }
  } else if (bk < 384){
    // =================== score role ===================
    __shared__ float hsh[H];
    __shared__ float dps[2][128];
    __shared__ float dpl[128];
    __shared__ float vsh2[128];
    __shared__ float pspart[2][128];
    const int b = (bk - 256) >> 2, q = (bk - 256) & 3;
    const unsigned* myhtags = htags + (size_t)b * 8 * 32;
    unsigned* mytag = pstags + (size_t)(b * 4 + q) * 32;
    if (tid < 128) vsh2[tid] = vvec[q * 128 + tid];
    for (int tau = 0; tau < S; ++tau){
      if (tid < 8){
        while (cloadu(myhtags + tid * 32) < (unsigned)(tau + 2)) __builtin_amdgcn_s_sleep(1);
      }
      __syncthreads();
      { float2 qq = cload2(hb + ((size_t)b * 2 + (tau & 1)) * H + 2 * tid);
        hsh[2*tid] = qq.x; hsh[2*tid + 1] = qq.y; }
      __syncthreads();
      // dp-slice: cols q*128+nl; halves over k
      {
        int nl = tid & 127, kh = tid >> 7;
        const float* w = W2T + (size_t)(kh * 256) * H + q * 128 + nl;
        float a = 0.f;
        #pragma unroll 8
        for (int k2 = 0; k2 < 256; ++k2)
          a = fmaf(w[(size_t)k2 * H], hsh[kh * 256 + k2], a);
        dps[kh][nl] = a;
      }
      __syncthreads();
      if (tid < 128) dpl[tid] = dps[0][tid] + dps[1][tid];
      __syncthreads();
      // partial scores over this 128-unit slice
      {
        int s = tid & 127, nh = tid >> 7;
        const float* Pp = Pt + ((size_t)b * H + q * 128 + nh * 64) * S + s;
        float cs = 0.f;
        #pragma unroll 4
        for (int n = 0; n < 64; ++n){
          float x = Pp[(size_t)n * S] + dpl[nh * 64 + n];
          cs = fmaf(vsh2[nh * 64 + n], tanh_(x), cs);
        }
        pspart[nh][s] = cs;
      }
      __syncthreads();
      if (tid < 64)
        cstore2(psbuf + ((size_t)b * 4 + q) * 128 + 2 * tid,
                pspart[0][2*tid] + pspart[1][2*tid],
                pspart[0][2*tid+1] + pspart[1][2*tid+1]);
      __syncthreads();   // drain ps publish before tag
      if (tid == 0) cstoreu(mytag, (unsigned)(tau + 1));
    }
  } else {
    // =================== owner role (argmax + softmax) ===================
    __shared__ float wm[2]; __shared__ int wi[2]; __shared__ float wsum[2];
    const int b = bk - 384;
    unsigned* mytop = tops + (size_t)b * 32;
    for (int t = 0; t < S; ++t){
      if (tid < 4){
        const unsigned* L = pstags + (size_t)(b * 4 + tid) * 32;
        while (cloadu(L) < (unsigned)(t + 1)) __builtin_amdgcn_s_sleep(1);
      }
      __syncthreads();
      float sc = 0.f;
      if (tid < 128){
        const float* pp = psbuf + (size_t)b * 512 + tid;
        sc = cloadf(pp) + cloadf(pp + 128) + cloadf(pp + 256) + cloadf(pp + 384);
        float mv = sc; int mi = tid;
        #pragma unroll
        for (int off = 32; off > 0; off >>= 1){
          float ov = __shfl_xor(mv, off, 64);
          int   oi = __shfl_xor(mi, off, 64);
          if (ov > mv || (ov == mv && oi < mi)){ mv = ov; mi = oi; }
        }
        if ((tid & 63) == 0){ wm[tid >> 6] = mv; wi[tid >> 6] = mi; }
      }
      __syncthreads();
      float mglob; int am;
      { float m0 = wm[0], m1 = wm[1];
        if (m1 > m0 || (m1 == m0 && wi[1] < wi[0])){ mglob = m1; am = wi[1]; }
        else { mglob = m0; am = wi[0]; } }
      // publish top IMMEDIATELY (psbuf reads done; no store drain needed for
      // correctness of top value itself since it is carried in the tag word)
      if (tid == 0) cstoreu(mytop, ((unsigned)(t + 1) << 8) | (unsigned)am);
      // off-path: log-softmax + out row t
      if (tid < 128){
        float se = __expf(sc - mglob);
        float ss = se;
        #pragma unroll
        for (int off = 32; off > 0; off >>= 1) ss += __shfl_xor(ss, off, 64);
        if ((tid & 63) == 0) wsum[tid >> 6] = ss;
      }
      __syncthreads();
      if (tid < 128){
        float lse = __logf(wsum[0] + wsum[1]);
        out[((size_t)b * S + t) * S + tid] = sc - mglob - lse;
      }
      __syncthreads();
    }
  }
}

extern "C" void kernel_launch(void* const* d_in, const int* in_sizes, int n_in,
                              void* d_out, int out_size, void* d_ws, size_t ws_size,
                              hipStream_t stream) {
  const float* inputs  = (const float*)d_in[0];
  const float* Wp      = (const float*)d_in[1];
  const float* bp      = (const float*)d_in[2];
  const float* eWih    = (const float*)d_in[3];
  const float* eWhh    = (const float*)d_in[4];
  const float* ebih    = (const float*)d_in[5];
  const float* ebhh    = (const float*)d_in[6];
  const float* dWih    = (const float*)d_in[7];
  const float* dWhh    = (const float*)d_in[8];
  const float* dbih    = (const float*)d_in[9];
  const float* dbhh    = (const float*)d_in[10];
  const float* W1      = (const float*)d_in[11];
  const float* W2      = (const float*)d_in[12];
  const float* v       = (const float*)d_in[13];
  float* out = (float*)d_out;

  float* ws = (float*)d_ws;
  float* E       = ws + OFF_E;    // reused as D after encoder
  float* enc_out = ws + OFF_EO;
  float* Pt      = ws + OFF_PT;
  float* WPe     = ws + OFF_WPE;
  float* WPd     = ws + OFF_WPD;
  float* W2T     = ws + OFF_W2T;
  float* hb      = ws + OFF_HB;
  float* c_buf   = ws + OFF_CB;
  float* psbuf   = ws + OFF_PS;
  float* M1      = ws + OFF_M1;
  float* bias_e  = ws + OFF_BE;
  float* dbias   = ws + OFF_DB;
  unsigned* enc_htags = (unsigned*)(ws + OFF_END);
  unsigned* dec_htags = enc_htags + 256 * 32;
  unsigned* pstags    = dec_htags + 256 * 32;
  unsigned* tops      = pstags + 128 * 32;

  // deterministic per launch: zero h buffers + all tag lines
  hipMemsetAsync(hb, 0, (size_t)B * 2 * H * sizeof(float), stream);
  hipMemsetAsync(enc_htags, 0, CTRL_U32 * sizeof(unsigned), stream);

  prep_misc<<<G4 / 256, 256, 0, stream>>>(eWih, Wp, bp, ebih, ebhh, dbih, dbhh,
                                          M1, bias_e, dbias);
  efill<<<(int)(SZ_E / 256), 256, 0, stream>>>(inputs, M1, bias_e, E);
  pack_whh<<<(int)(SZ_WP / 256), 256, 0, stream>>>(eWhh, WPe);
  pack_whh<<<(int)(SZ_WP / 256), 256, 0, stream>>>(dWhh, WPd);
  { dim3 g(H / 32, H / 32); transpose_k<<<g, 256, 0, stream>>>(W2, W2T, H, H); }

  encoder_kernel<<<256, 256, 0, stream>>>(WPe, E, hb, c_buf, enc_out, enc_htags);

  // D = enc_out @ dWih^T + dbias (into E's buffer; encoder is done with E)
  float* D = E;
  { dim3 grid(G4 / 64, (B * S) / 64);
    gemm_nt<0><<<grid, 256, 0, stream>>>(enc_out, dWih, dbias, D, B * S, G4, H); }
  { dim3 grid(H / 64, (B * S) / 64);
    gemm_nt<1><<<grid, 256, 0, stream>>>(enc_out, W1, nullptr, Pt, B * S, H, H); }

  decoder_kernel<<<416, 256, 0, stream>>>(WPd, D, dbias, W2T, Pt, v, c_buf,
                                          enc_out, hb, psbuf,
                                          dec_htags, pstags, tops, out);
  (void)in_sizes; (void)n_in; (void)out_size; (void)ws_size;
}